// Round 11
// baseline (675.197 us; speedup 1.0000x reference)
//
#include <hip/hip_runtime.h>
#include <math.h>

#define CDIM 192
#define HW 65536

typedef __attribute__((ext_vector_type(8))) short short8;
typedef __attribute__((ext_vector_type(4))) float f32x4;

__device__ __forceinline__ ushort f2bf(float f) {
  uint u = __float_as_uint(f);
  uint r = (u + 0x7fffu + ((u >> 16) & 1u)) >> 16;
  return (ushort)r;
}
__device__ __forceinline__ float bf2f(ushort u) {
  return __uint_as_float(((uint)u) << 16);
}

// row r (0..383) of a head: c = r>>4, h1 = (r>>2)&3, w1 = r&3
// element offset of (b, head, r, hs, ws=0) in NCHW (2,192,256,256)
__device__ __forceinline__ size_t rowbase(int b, int head, int r, int hs) {
  int c = r >> 4, h1 = (r >> 2) & 3, w1 = r & 3;
  return ((size_t)(b * CDIM + head * 24 + c) << 16) +
         (size_t)((h1 << 6) + hs) * 256 + (w1 << 6);
}

// ---------------- zero the norm-accumulator buffer (12288 floats)
__global__ __launch_bounds__(256) void zero_nrm_kernel(float* __restrict__ p) {
  p[(blockIdx.x << 8) + threadIdx.x] = 0.f;
}

// ---------------- cast+transpose: NCHW fp32 -> NHWC bf16  [b][p][192]
// z selects (xu -> out0) vs (xd -> out1)
__global__ __launch_bounds__(256) void cast_f32_nhwc_kernel(
    const float* __restrict__ in0, const float* __restrict__ in1,
    ushort* __restrict__ out0, ushort* __restrict__ out1) {
  __shared__ ushort T[64][200];          // stride 400B = 25*16 (b128-aligned)
  const int p0 = blockIdx.x << 6, b = blockIdx.y;
  const float* in = blockIdx.z ? in1 : in0;
  ushort* out = blockIdx.z ? out1 : out0;
  const int tid = threadIdx.x;
#pragma unroll
  for (int it = 0; it < 12; ++it) {      // 192c x 64p fp32 = 3072 float4
    int idx = (it << 8) + tid;
    int c = idx >> 4, p4 = (idx & 15) << 2;
    float4 v = *(const float4*)&in[((size_t)(b * CDIM + c) << 16) + p0 + p4];
    T[p4 + 0][c] = f2bf(v.x);
    T[p4 + 1][c] = f2bf(v.y);
    T[p4 + 2][c] = f2bf(v.z);
    T[p4 + 3][c] = f2bf(v.w);
  }
  __syncthreads();
#pragma unroll
  for (int it = 0; it < 6; ++it) {       // 64p x 192c bf16 = 1536 uint4
    int idx = (it << 8) + tid;
    int p = idx / 24, c8 = (idx % 24) << 3;
    *(uint4*)&out[((size_t)(b * HW + p0 + p)) * CDIM + c8] =
        *(uint4*)&T[p][c8];
  }
}

// ---------------- cast+transpose: NCHW bf16 -> NHWC bf16
__global__ __launch_bounds__(256) void cast_bf16_nhwc_kernel(
    const ushort* __restrict__ in, ushort* __restrict__ out) {
  __shared__ ushort T[64][200];
  const int p0 = blockIdx.x << 6, b = blockIdx.y;
  const int tid = threadIdx.x;
#pragma unroll
  for (int it = 0; it < 6; ++it) {       // 192c x 64p bf16 = 1536 uint4
    int idx = (it << 8) + tid;
    int c = idx >> 3, p8 = (idx & 7) << 3;
    uint4 v = *(const uint4*)&in[((size_t)(b * CDIM + c) << 16) + p0 + p8];
    const ushort* pv = (const ushort*)&v;
#pragma unroll
    for (int q = 0; q < 8; ++q) T[p8 + q][c] = pv[q];
  }
  __syncthreads();
#pragma unroll
  for (int it = 0; it < 6; ++it) {
    int idx = (it << 8) + tid;
    int p = idx / 24, c8 = (idx % 24) << 3;
    *(uint4*)&out[((size_t)(b * HW + p0 + p)) * CDIM + c8] =
        *(uint4*)&T[p][c8];
  }
}

// ---------------- conv1x1 via bf16 MFMA: X NHWC bf16, W fp32 [o][c]
// tile 64o x 256p, K=192 in 3 chunks of 64. 4 waves, each 64o x 64p.
template <int OUTF32>
__global__ __launch_bounds__(256) void conv_mfma_kernel(
    const ushort* __restrict__ Xt, const float* __restrict__ w,
    const float* __restrict__ bias, void* __restrict__ outv) {
  __shared__ ushort WL[64][200];         // [o][c], stride 400B
  __shared__ ushort XL[256][72];         // [p][c-chunk 64], stride 144B
  const int p0 = blockIdx.x << 8;
  const int o0 = blockIdx.y << 6;
  const int b  = blockIdx.z;
  const int tid = threadIdx.x;
  const int wave = tid >> 6, lane = tid & 63;
  const int lr = lane & 15, lk = lane >> 4;
  // stage W (fp32 -> bf16), 64 x 192
#pragma unroll
  for (int it = 0; it < 12; ++it) {
    int idx = (it << 8) + tid;
    int o = idx / 48, c4 = (idx % 48) << 2;
    float4 v = *(const float4*)&w[(o0 + o) * CDIM + c4];
    ushort4 u = make_ushort4(f2bf(v.x), f2bf(v.y), f2bf(v.z), f2bf(v.w));
    *(ushort4*)&WL[o][c4] = u;
  }
  f32x4 acc[4][4] = {};
  const size_t xbase = ((size_t)(b * HW + p0)) * CDIM;
  for (int kt = 0; kt < 3; ++kt) {
    __syncthreads();
#pragma unroll
    for (int it = 0; it < 8; ++it) {     // 256p x 64c = 2048 uint4
      int idx = (it << 8) + tid;
      int p = idx >> 3, c8 = (idx & 7) << 3;
      *(uint4*)&XL[p][c8] =
          *(const uint4*)&Xt[xbase + (size_t)p * CDIM + kt * 64 + c8];
    }
    __syncthreads();
#pragma unroll
    for (int kk = 0; kk < 2; ++kk) {
      short8 aF[4], bF[4];
#pragma unroll
      for (int m = 0; m < 4; ++m)
        aF[m] = *(const short8*)&WL[(m << 4) + lr][kt * 64 + (kk << 5) + (lk << 3)];
#pragma unroll
      for (int n = 0; n < 4; ++n)
        bF[n] = *(const short8*)&XL[(wave << 6) + (n << 4) + lr][(kk << 5) + (lk << 3)];
#pragma unroll
      for (int m = 0; m < 4; ++m)
#pragma unroll
        for (int n = 0; n < 4; ++n)
          acc[m][n] =
              __builtin_amdgcn_mfma_f32_16x16x32_bf16(aF[m], bF[n], acc[m][n], 0, 0, 0);
    }
  }
#pragma unroll
  for (int m = 0; m < 4; ++m)
#pragma unroll
    for (int reg = 0; reg < 4; ++reg) {
      int i = o0 + (m << 4) + (lk << 2) + reg;
      float bo = bias[i];
      size_t ob = ((size_t)(b * CDIM + i) << 16) + p0 + (wave << 6) + lr;
#pragma unroll
      for (int n = 0; n < 4; ++n) {
        float v = acc[m][n][reg] + bo;
        if (OUTF32)
          ((float*)outv)[ob + (n << 4)] = v;
        else
          ((ushort*)outv)[ob + (n << 4)] = f2bf(v);
      }
    }
}

// ---------------- depthwise 3x3 on NCHW bf16 -> bf16 heads layout,
// fused per-heads-row sum-of-squares accumulation (atomics into nrms)
__global__ __launch_bounds__(256) void dw3x3_bf16_kernel(
    const ushort* __restrict__ in, const float* __restrict__ wdw,
    ushort* __restrict__ outb, float* __restrict__ nrms) {
  size_t idx = ((size_t)blockIdx.x << 8) + threadIdx.x;
  int x0 = (int)(idx & 63) << 2;
  int y  = (int)((idx >> 6) & 255);
  int bc = (int)(idx >> 14);
  int ch = bc % CDIM, b = bc / CDIM;
  const ushort* ip = in + ((size_t)bc << 16);
  const float* wp = wdw + ch * 9;
  float wv[9];
#pragma unroll
  for (int k = 0; k < 9; ++k) wv[k] = wp[k];
  float r[3][6];
#pragma unroll
  for (int dy = 0; dy < 3; ++dy) {
    int yy = y + dy - 1;
    bool yok = (yy >= 0) && (yy < 256);
#pragma unroll
    for (int dx = 0; dx < 6; ++dx) {
      int xx = x0 + dx - 1;
      bool ok = yok && (xx >= 0) && (xx < 256);
      r[dy][dx] = ok ? bf2f(ip[(size_t)yy * 256 + xx]) : 0.f;
    }
  }
  float o_[4];
  float ss = 0.f;
#pragma unroll
  for (int j = 0; j < 4; ++j) {
    float a = 0.f;
#pragma unroll
    for (int dy = 0; dy < 3; ++dy)
#pragma unroll
      for (int dx = 0; dx < 3; ++dx)
        a = fmaf(r[dy][j + dx], wv[dy * 3 + dx], a);
    o_[j] = a;
    float q = bf2f(f2bf(a));           // square the ROUNDED value
    ss = fmaf(q, q, ss);
  }
  int head = ch / 24, c = ch % 24;
  int h1 = y >> 6, hs = y & 63, w1 = x0 >> 6, ws0 = x0 & 63;
  int bh = (b << 3) + head;
  int rr = (c << 4) + (h1 << 2) + w1;
  *(ushort4*)&outb[((size_t)(bh * 384 + rr) << 12) + (hs << 6) + ws0] =
      make_ushort4(f2bf(o_[0]), f2bf(o_[1]), f2bf(o_[2]), f2bf(o_[3]));
  // 16-lane-group reduce (one heads-row per group) + 1 atomic per group
  const int lane = threadIdx.x & 63;
#pragma unroll
  for (int off = 8; off; off >>= 1) ss += __shfl_xor(ss, off, 64);
  if ((lane & 15) == 0) atomicAdd(&nrms[bh * 384 + rr], ss);
}

// ---------------- fused mdc (v2): all 4 kernel sizes from one staged tile.
// tile 32x32, thread = 4-wide strip; b128 row loads, 24:1 FMA:LDS ratio.
// NOTE: the ~3.9e7 SQ_LDS_BANK_CONFLICT here are 2-way (free per m136);
// v3/v4/v5/v6 restructurings all regressed — do not re-litigate.
__global__ __launch_bounds__(256) void mdc_fused_kernel(
    const ushort* __restrict__ in, const float* __restrict__ w3,
    const float* __restrict__ w5, const float* __restrict__ w7,
    const float* __restrict__ w9, ushort* __restrict__ out) {
  __shared__ float s[4][40][40];
  const int bz = blockIdx.z;
  const int b = bz / 48, g = bz % 48;
  const int x0 = blockIdx.x << 5, y0 = blockIdx.y << 5;
  const ushort* inb = in + (((size_t)b * CDIM + 4 * g) << 16);
  const int tx = threadIdx.x & 7;        // x-chunk (4 wide)
  const int ty = threadIdx.x >> 3;       // y 0..31
  const int yo = y0 + ty, xo = x0 + (tx << 2);
  // prefetch sigmoid inputs (independent; hides tail latency)
  ushort4 upre[4];
#pragma unroll
  for (int sel = 0; sel < 4; ++sel) {
    int oc = sel * 48 + g;
    upre[sel] = *(const ushort4*)&in[(((size_t)b * CDIM + oc) << 16) +
                                     (size_t)yo * 256 + xo];
  }
  // stage: 4ch x 40rows x 40cols, 4-elem chunks (never straddle 0/256)
  for (int idx = threadIdx.x; idx < 1600; idx += 256) {
    int rowid = idx / 10, c = idx % 10;
    int i = rowid / 40, yy = rowid % 40;
    int y = y0 + yy - 4;
    int xs = x0 + (c << 2) - 4;
    float4 v = make_float4(0.f, 0.f, 0.f, 0.f);
    if (y >= 0 && y < 256 && xs >= 0 && xs < 256) {
      ushort4 u = *(const ushort4*)&inb[((size_t)i << 16) + (size_t)y * 256 + xs];
      v = make_float4(bf2f(u.x), bf2f(u.y), bf2f(u.z), bf2f(u.w));
    }
    *(float4*)&s[i][yy][c << 2] = v;
  }
  __syncthreads();
  float a3[4] = {}, a5[4] = {}, a7[4] = {}, a9[4] = {};
#pragma unroll 1
  for (int i = 0; i < 4; ++i) {
    const float* w9p = w9 + (g * 4 + i) * 81;
    const float* w7p = w7 + (g * 4 + i) * 49;
    const float* w5p = w5 + (g * 4 + i) * 25;
    const float* w3p = w3 + (g * 4 + i) * 9;
#pragma unroll
    for (int ky = 0; ky < 9; ++ky) {
      float row[12];
      *(float4*)&row[0] = *(const float4*)&s[i][ty + ky][(tx << 2)];
      *(float4*)&row[4] = *(const float4*)&s[i][ty + ky][(tx << 2) + 4];
      *(float4*)&row[8] = *(const float4*)&s[i][ty + ky][(tx << 2) + 8];
#pragma unroll
      for (int kx = 0; kx < 9; ++kx) {
        float w = w9p[ky * 9 + kx];
#pragma unroll
        for (int j = 0; j < 4; ++j) a9[j] = fmaf(row[j + kx], w, a9[j]);
      }
      if (ky >= 1 && ky <= 7) {
#pragma unroll
        for (int kx = 0; kx < 7; ++kx) {
          float w = w7p[(ky - 1) * 7 + kx];
#pragma unroll
          for (int j = 0; j < 4; ++j) a7[j] = fmaf(row[j + kx + 1], w, a7[j]);
        }
      }
      if (ky >= 2 && ky <= 6) {
#pragma unroll
        for (int kx = 0; kx < 5; ++kx) {
          float w = w5p[(ky - 2) * 5 + kx];
#pragma unroll
          for (int j = 0; j < 4; ++j) a5[j] = fmaf(row[j + kx + 2], w, a5[j]);
        }
      }
      if (ky >= 3 && ky <= 5) {
#pragma unroll
        for (int kx = 0; kx < 3; ++kx) {
          float w = w3p[(ky - 3) * 3 + kx];
#pragma unroll
          for (int j = 0; j < 4; ++j) a3[j] = fmaf(row[j + kx + 3], w, a3[j]);
        }
      }
    }
  }
#pragma unroll
  for (int sel = 0; sel < 4; ++sel) {
    const float* ap = (sel == 0) ? a3 : (sel == 1) ? a5 : (sel == 2) ? a7 : a9;
    int oc = sel * 48 + g;
    size_t off = (((size_t)b * CDIM + oc) << 16) + (size_t)yo * 256 + xo;
    ushort4 u = upre[sel];
    float s0 = __builtin_amdgcn_rcpf(1.f + __expf(-bf2f(u.x)));
    float s1 = __builtin_amdgcn_rcpf(1.f + __expf(-bf2f(u.y)));
    float s2 = __builtin_amdgcn_rcpf(1.f + __expf(-bf2f(u.z)));
    float s3 = __builtin_amdgcn_rcpf(1.f + __expf(-bf2f(u.w)));
    *(ushort4*)&out[off] = make_ushort4(f2bf(s0 * ap[0]), f2bf(s1 * ap[1]),
                                        f2bf(s2 * ap[2]), f2bf(s3 * ap[3]));
  }
}

// ---------------- QK^T partials: bf16 MFMA, 128x128 tile, split-K=4
__global__ __launch_bounds__(256) void qk_mfma_kernel(
    const ushort* __restrict__ Qb, const ushort* __restrict__ Kb,
    float* __restrict__ part) {
  __shared__ ushort as_[128][72];
  __shared__ ushort bs_[128][72];
  const int bz = blockIdx.z, bh = bz >> 2, ks = bz & 3;
  const int i0 = blockIdx.y << 7, j0 = blockIdx.x << 7;
  const int tid = threadIdx.x;
  const int wave = tid >> 6, lane = tid & 63;
  const int wr = wave >> 1, wc = wave & 1;
  const int lr = lane & 15, lk = lane >> 4;
  const size_t qbase = ((size_t)(bh * 384 + i0) << 12) + (ks << 10);
  const size_t kbase = ((size_t)(bh * 384 + j0) << 12) + (ks << 10);
  f32x4 acc[4][4] = {};
  for (int kt = 0; kt < 16; ++kt) {
#pragma unroll
    for (int e = 0; e < 4; ++e) {
      int chunk = (e << 8) + tid;
      int row = chunk >> 3, c8 = (chunk & 7) << 3;
      *(uint4*)&as_[row][c8] =
          *(const uint4*)&Qb[qbase + ((size_t)row << 12) + (kt << 6) + c8];
      *(uint4*)&bs_[row][c8] =
          *(const uint4*)&Kb[kbase + ((size_t)row << 12) + (kt << 6) + c8];
    }
    __syncthreads();
#pragma unroll
    for (int kk = 0; kk < 2; ++kk) {
      short8 aF[4], bF[4];
#pragma unroll
      for (int m = 0; m < 4; ++m)
        aF[m] = *(const short8*)&as_[(wr << 6) + (m << 4) + lr][(kk << 5) + (lk << 3)];
#pragma unroll
      for (int n = 0; n < 4; ++n)
        bF[n] = *(const short8*)&bs_[(wc << 6) + (n << 4) + lr][(kk << 5) + (lk << 3)];
#pragma unroll
      for (int m = 0; m < 4; ++m)
#pragma unroll
        for (int n = 0; n < 4; ++n)
          acc[m][n] =
              __builtin_amdgcn_mfma_f32_16x16x32_bf16(aF[m], bF[n], acc[m][n], 0, 0, 0);
    }
    __syncthreads();
  }
  float* pbase = part + (size_t)(ks * 16 + bh) * 384 * 384;
#pragma unroll
  for (int m = 0; m < 4; ++m)
#pragma unroll
    for (int reg = 0; reg < 4; ++reg) {
      int i = i0 + (wr << 6) + (m << 4) + (lk << 2) + reg;
#pragma unroll
      for (int n = 0; n < 4; ++n) {
        int j = j0 + (wc << 6) + (n << 4) + lr;
        pbase[(size_t)i * 384 + j] = acc[m][n][reg];
      }
    }
}

// ---------------- sum partials, inv-norm scale, softmax, write bf16 P
__global__ __launch_bounds__(384) void softmax_kernel(
    const float* __restrict__ part, const float* __restrict__ nrms,
    const float* __restrict__ temp, ushort* __restrict__ Pb) {
  const int row = blockIdx.x;
  const int bh = row / 384;
  const int head = bh & 7;
  const int tid = threadIdx.x;
  const size_t off = (size_t)row * 384 + tid;
  float s = part[off] + part[off + 2359296] + part[off + 4718592] +
            part[off + 7077888];
  float iq = 1.f / fmaxf(sqrtf(nrms[row]), 1e-12f);
  float ik = 1.f / fmaxf(sqrtf(nrms[6144 + bh * 384 + tid]), 1e-12f);
  float v = s * temp[head] * iq * ik;
  __shared__ float red[6];
  float m = v;
#pragma unroll
  for (int o = 32; o; o >>= 1) m = fmaxf(m, __shfl_down(m, o, 64));
  if ((tid & 63) == 0) red[tid >> 6] = m;
  __syncthreads();
  float bm = fmaxf(fmaxf(fmaxf(red[0], red[1]), fmaxf(red[2], red[3])),
                   fmaxf(red[4], red[5]));
  __syncthreads();
  float e = __expf(v - bm);
  float ss = e;
#pragma unroll
  for (int o = 32; o; o >>= 1) ss += __shfl_down(ss, o, 64);
  if ((tid & 63) == 0) red[tid >> 6] = ss;
  __syncthreads();
  float bs = red[0] + red[1] + red[2] + red[3] + red[4] + red[5];
  Pb[off] = f2bf(e * __builtin_amdgcn_rcpf(bs));
}

// ---------------- pack V: bf16 NCHW -> bf16 token-major [bh][t][384]
__global__ __launch_bounds__(256) void pack_v_kernel(
    const ushort* __restrict__ v1, ushort* __restrict__ Vb) {
  __shared__ ushort st[384][72];
  const int hs = blockIdx.x, bh = blockIdx.y;
  const int b = bh >> 3, head = bh & 7;
  const int tid = threadIdx.x;
#pragma unroll
  for (int e = 0; e < 12; ++e) {
    int idx = (e << 8) + tid;
    int r = idx >> 3, w8 = (idx & 7) << 3;
    *(uint4*)&st[r][w8] = *(const uint4*)&v1[rowbase(b, head, r, hs) + w8];
  }
  __syncthreads();
  const size_t vb0 = ((size_t)bh * 4096 + (hs << 6)) * 384;
#pragma unroll
  for (int e = 0; e < 12; ++e) {
    int chunk = (e << 8) + tid;
    int trow = chunk & 63, c8 = (chunk >> 6) << 3;
    ushort tmp[8];
#pragma unroll
    for (int q = 0; q < 8; ++q) tmp[q] = st[c8 + q][trow];
    *(uint4*)&Vb[vb0 + (size_t)trow * 384 + c8] = *(uint4*)tmp;
  }
}

// ---------------- O = P @ V : bf16 MFMA -> bf16 NCHW heads-merged
__global__ __launch_bounds__(256) void pv_mfma_kernel(
    const ushort* __restrict__ Pb, const ushort* __restrict__ Vb,
    ushort* __restrict__ outh) {
  __shared__ ushort as_[128][72];
  __shared__ ushort bs_[128][72];
  const int bh = blockIdx.z, b = bh >> 3, head = bh & 7;
  const int i0 = blockIdx.y << 7, t0 = blockIdx.x << 7;
  const int tid = threadIdx.x;
  const int wave = tid >> 6, lane = tid & 63;
  const int wr = wave >> 1, wc = wave & 1;
  const int lr = lane & 15, lk = lane >> 4;
  const size_t pbase = (size_t)(bh * 384 + i0) * 384;
  const size_t vbase = ((size_t)bh * 4096 + t0) * 384;
  f32x4 acc[4][4] = {};
  for (int kt = 0; kt < 6; ++kt) {
#pragma unroll
    for (int e = 0; e < 4; ++e) {
      int chunk = (e << 8) + tid;
      int row = chunk >> 3, c8 = (chunk & 7) << 3;
      *(uint4*)&as_[row][c8] =
          *(const uint4*)&Pb[pbase + (size_t)row * 384 + (kt << 6) + c8];
      *(uint4*)&bs_[row][c8] =
          *(const uint4*)&Vb[vbase + (size_t)row * 384 + (kt << 6) + c8];
    }
    __syncthreads();
#pragma unroll
    for (int kk = 0; kk < 2; ++kk) {
      short8 aF[4], bF[4];
#pragma unroll
      for (int m = 0; m < 4; ++m)
        aF[m] = *(const short8*)&as_[(wr << 6) + (m << 4) + lr][(kk << 5) + (lk << 3)];
#pragma unroll
      for (int n = 0; n < 4; ++n)
        bF[n] = *(const short8*)&bs_[(wc << 6) + (n << 4) + lr][(kk << 5) + (lk << 3)];
#pragma unroll
      for (int m = 0; m < 4; ++m)
#pragma unroll
        for (int n = 0; n < 4; ++n)
          acc[m][n] =
              __builtin_amdgcn_mfma_f32_16x16x32_bf16(aF[m], bF[n], acc[m][n], 0, 0, 0);
    }
    __syncthreads();
  }
#pragma unroll
  for (int m = 0; m < 4; ++m)
#pragma unroll
    for (int reg = 0; reg < 4; ++reg) {
      int i = i0 + (wr << 6) + (m << 4) + (lk << 2) + reg;
#pragma unroll
      for (int n = 0; n < 4; ++n) {
        int t = t0 + (wc << 6) + (n << 4) + lr;
        outh[rowbase(b, head, i, t >> 6) + (t & 63)] = f2bf(acc[m][n][reg]);
      }
    }
}

extern "C" void kernel_launch(void* const* d_in, const int* in_sizes, int n_in,
                              void* d_out, int out_size, void* d_ws,
                              size_t ws_size, hipStream_t stream) {
  const float* xu     = (const float*)d_in[0];
  const float* xd     = (const float*)d_in[1];
  const float* temp   = (const float*)d_in[2];
  const float* q1_w   = (const float*)d_in[3];
  const float* q1_b   = (const float*)d_in[4];
  const float* k1_w   = (const float*)d_in[5];
  const float* k1_b   = (const float*)d_in[6];
  const float* v1_w   = (const float*)d_in[7];
  const float* v1_b   = (const float*)d_in[8];
  const float* mdcq_w = (const float*)d_in[9];
  const float* mdck_w = (const float*)d_in[10];
  const float* mdc1_w = (const float*)d_in[11];
  const float* mdc2_w = (const float*)d_in[12];
  const float* mdc3_w = (const float*)d_in[13];
  const float* mdc4_w = (const float*)d_in[14];
  const float* proj_w = (const float*)d_in[15];
  const float* proj_b = (const float*)d_in[16];
  float* out = (float*)d_out;

  const size_t SZ = (size_t)2 * CDIM * HW * 2;   // bytes of one bf16 tensor
  char* W = (char*)d_ws;
  ushort* A0 = (ushort*)(W + 0 * SZ);    // Xut -> kpre
  ushort* A1 = (ushort*)(W + 1 * SZ);    // Xdt -> OH (heads-merged NCHW bf16)
  ushort* A2 = (ushort*)(W + 2 * SZ);    // qpre -> vpre -> OHt
  ushort* A3 = (ushort*)(W + 3 * SZ);    // Qb  -> v1 (mdc out)
  ushort* A4 = (ushort*)(W + 4 * SZ);    // Kb  -> Vb
  float*  PART = (float*)(W + 5 * SZ);                   // 4x16x384x384 fp32
  ushort* Pb   = (ushort*)(W + 5 * SZ + 37748736);       // bf16 P
  float*  NRM  = (float*)(W + 5 * SZ + 37748736 + 4718592);  // 12288 sumsq

  dim3 b256(256);
  dim3 gcast(1024, 2, 2);
  dim3 gconv(256, 3, 2);

  // zero norm accumulators (re-done every call -> graph-safe)
  zero_nrm_kernel<<<48, b256, 0, stream>>>(NRM);
  // input casts to NHWC bf16 (one launch, z selects tensor)
  cast_f32_nhwc_kernel<<<gcast, b256, 0, stream>>>(xu, xd, A0, A1);
  // q branch (dw accumulates sumsq into NRM[0:6144])
  conv_mfma_kernel<0><<<gconv, b256, 0, stream>>>(A0, q1_w, q1_b, A2);
  dw3x3_bf16_kernel<<<24576, b256, 0, stream>>>(A2, mdcq_w, A3, NRM);
  // k branch (A0 free after conv-q; sumsq into NRM[6144:12288])
  conv_mfma_kernel<0><<<gconv, b256, 0, stream>>>(A1, k1_w, k1_b, A0);
  dw3x3_bf16_kernel<<<24576, b256, 0, stream>>>(A0, mdck_w, A4, NRM + 6144);
  // attention logits (split-K=4) + fused inv-norm/scale/softmax
  qk_mfma_kernel<<<dim3(3, 3, 64), b256, 0, stream>>>(A3, A4, PART);
  softmax_kernel<<<6144, dim3(384), 0, stream>>>(PART, NRM, temp, Pb);
  // v branch: conv (Xdt still in A1), fused mdc into A3 (Qb dead), pack to A4
  conv_mfma_kernel<0><<<gconv, b256, 0, stream>>>(A1, v1_w, v1_b, A2);
  mdc_fused_kernel<<<dim3(8, 8, 96), b256, 0, stream>>>(
      A2, mdc1_w, mdc2_w, mdc3_w, mdc4_w, A3);
  pack_v_kernel<<<dim3(64, 16), b256, 0, stream>>>(A3, A4);
  // O = P @ V -> heads-merged NCHW bf16 in A1 (Xdt dead)
  pv_mfma_kernel<<<dim3(32, 3, 16), b256, 0, stream>>>(Pb, A4, A1);
  // cast OH to NHWC, final projection -> fp32 d_out
  cast_bf16_nhwc_kernel<<<dim3(1024, 2), b256, 0, stream>>>(A1, A2);
  conv_mfma_kernel<1><<<gconv, b256, 0, stream>>>(A2, proj_w, proj_b, out);
}

// Round 12
// 644.809 us; speedup vs baseline: 1.0471x; 1.0471x over previous
//
#include <hip/hip_runtime.h>
#include <math.h>

#define CDIM 192
#define HW 65536

typedef __attribute__((ext_vector_type(8))) short short8;
typedef __attribute__((ext_vector_type(4))) float f32x4;

__device__ __forceinline__ ushort f2bf(float f) {
  uint u = __float_as_uint(f);
  uint r = (u + 0x7fffu + ((u >> 16) & 1u)) >> 16;
  return (ushort)r;
}
__device__ __forceinline__ float bf2f(ushort u) {
  return __uint_as_float(((uint)u) << 16);
}

// row r (0..383) of a head: c = r>>4, h1 = (r>>2)&3, w1 = r&3
// element offset of (b, head, r, hs, ws=0) in NCHW (2,192,256,256)
__device__ __forceinline__ size_t rowbase(int b, int head, int r, int hs) {
  int c = r >> 4, h1 = (r >> 2) & 3, w1 = r & 3;
  return ((size_t)(b * CDIM + head * 24 + c) << 16) +
         (size_t)((h1 << 6) + hs) * 256 + (w1 << 6);
}

// ---------------- cast+transpose: NCHW fp32 -> NHWC bf16  [b][p][192]
__global__ __launch_bounds__(256) void cast_f32_nhwc_kernel(
    const float* __restrict__ in, ushort* __restrict__ out) {
  __shared__ ushort T[64][200];          // stride 400B = 25*16 (b128-aligned)
  const int p0 = blockIdx.x << 6, b = blockIdx.y;
  const int tid = threadIdx.x;
#pragma unroll
  for (int it = 0; it < 12; ++it) {      // 192c x 64p fp32 = 3072 float4
    int idx = (it << 8) + tid;
    int c = idx >> 4, p4 = (idx & 15) << 2;
    float4 v = *(const float4*)&in[((size_t)(b * CDIM + c) << 16) + p0 + p4];
    T[p4 + 0][c] = f2bf(v.x);
    T[p4 + 1][c] = f2bf(v.y);
    T[p4 + 2][c] = f2bf(v.z);
    T[p4 + 3][c] = f2bf(v.w);
  }
  __syncthreads();
#pragma unroll
  for (int it = 0; it < 6; ++it) {       // 64p x 192c bf16 = 1536 uint4
    int idx = (it << 8) + tid;
    int p = idx / 24, c8 = (idx % 24) << 3;
    *(uint4*)&out[((size_t)(b * HW + p0 + p)) * CDIM + c8] =
        *(uint4*)&T[p][c8];
  }
}

// ---------------- cast+transpose: NCHW bf16 -> NHWC bf16
__global__ __launch_bounds__(256) void cast_bf16_nhwc_kernel(
    const ushort* __restrict__ in, ushort* __restrict__ out) {
  __shared__ ushort T[64][200];
  const int p0 = blockIdx.x << 6, b = blockIdx.y;
  const int tid = threadIdx.x;
#pragma unroll
  for (int it = 0; it < 6; ++it) {       // 192c x 64p bf16 = 1536 uint4
    int idx = (it << 8) + tid;
    int c = idx >> 3, p8 = (idx & 7) << 3;
    uint4 v = *(const uint4*)&in[((size_t)(b * CDIM + c) << 16) + p0 + p8];
    const ushort* pv = (const ushort*)&v;
#pragma unroll
    for (int q = 0; q < 8; ++q) T[p8 + q][c] = pv[q];
  }
  __syncthreads();
#pragma unroll
  for (int it = 0; it < 6; ++it) {
    int idx = (it << 8) + tid;
    int p = idx / 24, c8 = (idx % 24) << 3;
    *(uint4*)&out[((size_t)(b * HW + p0 + p)) * CDIM + c8] =
        *(uint4*)&T[p][c8];
  }
}

// ---------------- conv1x1 via bf16 MFMA: X NHWC bf16, W fp32 [o][c]
// tile 64o x 256p, K=192 in 3 chunks of 64. 4 waves, each 64o x 64p.
template <int OUTF32>
__global__ __launch_bounds__(256) void conv_mfma_kernel(
    const ushort* __restrict__ Xt, const float* __restrict__ w,
    const float* __restrict__ bias, void* __restrict__ outv) {
  __shared__ ushort WL[64][200];         // [o][c], stride 400B
  __shared__ ushort XL[256][72];         // [p][c-chunk 64], stride 144B
  const int p0 = blockIdx.x << 8;
  const int o0 = blockIdx.y << 6;
  const int b  = blockIdx.z;
  const int tid = threadIdx.x;
  const int wave = tid >> 6, lane = tid & 63;
  const int lr = lane & 15, lk = lane >> 4;
  // stage W (fp32 -> bf16), 64 x 192
#pragma unroll
  for (int it = 0; it < 12; ++it) {
    int idx = (it << 8) + tid;
    int o = idx / 48, c4 = (idx % 48) << 2;
    float4 v = *(const float4*)&w[(o0 + o) * CDIM + c4];
    ushort4 u = make_ushort4(f2bf(v.x), f2bf(v.y), f2bf(v.z), f2bf(v.w));
    *(ushort4*)&WL[o][c4] = u;
  }
  f32x4 acc[4][4] = {};
  const size_t xbase = ((size_t)(b * HW + p0)) * CDIM;
  for (int kt = 0; kt < 3; ++kt) {
    __syncthreads();
#pragma unroll
    for (int it = 0; it < 8; ++it) {     // 256p x 64c = 2048 uint4
      int idx = (it << 8) + tid;
      int p = idx >> 3, c8 = (idx & 7) << 3;
      *(uint4*)&XL[p][c8] =
          *(const uint4*)&Xt[xbase + (size_t)p * CDIM + kt * 64 + c8];
    }
    __syncthreads();
#pragma unroll
    for (int kk = 0; kk < 2; ++kk) {
      short8 aF[4], bF[4];
#pragma unroll
      for (int m = 0; m < 4; ++m)
        aF[m] = *(const short8*)&WL[(m << 4) + lr][kt * 64 + (kk << 5) + (lk << 3)];
#pragma unroll
      for (int n = 0; n < 4; ++n)
        bF[n] = *(const short8*)&XL[(wave << 6) + (n << 4) + lr][(kk << 5) + (lk << 3)];
#pragma unroll
      for (int m = 0; m < 4; ++m)
#pragma unroll
        for (int n = 0; n < 4; ++n)
          acc[m][n] =
              __builtin_amdgcn_mfma_f32_16x16x32_bf16(aF[m], bF[n], acc[m][n], 0, 0, 0);
    }
  }
#pragma unroll
  for (int m = 0; m < 4; ++m)
#pragma unroll
    for (int reg = 0; reg < 4; ++reg) {
      int i = o0 + (m << 4) + (lk << 2) + reg;
      float bo = bias[i];
      size_t ob = ((size_t)(b * CDIM + i) << 16) + p0 + (wave << 6) + lr;
#pragma unroll
      for (int n = 0; n < 4; ++n) {
        float v = acc[m][n][reg] + bo;
        if (OUTF32)
          ((float*)outv)[ob + (n << 4)] = v;
        else
          ((ushort*)outv)[ob + (n << 4)] = f2bf(v);
      }
    }
}

// ---------------- depthwise 3x3 on NCHW bf16 -> bf16 heads layout
__global__ __launch_bounds__(256) void dw3x3_bf16_kernel(
    const ushort* __restrict__ in, const float* __restrict__ wdw,
    ushort* __restrict__ outb) {
  size_t idx = ((size_t)blockIdx.x << 8) + threadIdx.x;
  int x0 = (int)(idx & 63) << 2;
  int y  = (int)((idx >> 6) & 255);
  int bc = (int)(idx >> 14);
  int ch = bc % CDIM, b = bc / CDIM;
  const ushort* ip = in + ((size_t)bc << 16);
  const float* wp = wdw + ch * 9;
  float wv[9];
#pragma unroll
  for (int k = 0; k < 9; ++k) wv[k] = wp[k];
  float r[3][6];
#pragma unroll
  for (int dy = 0; dy < 3; ++dy) {
    int yy = y + dy - 1;
    bool yok = (yy >= 0) && (yy < 256);
#pragma unroll
    for (int dx = 0; dx < 6; ++dx) {
      int xx = x0 + dx - 1;
      bool ok = yok && (xx >= 0) && (xx < 256);
      r[dy][dx] = ok ? bf2f(ip[(size_t)yy * 256 + xx]) : 0.f;
    }
  }
  float o_[4];
#pragma unroll
  for (int j = 0; j < 4; ++j) {
    float a = 0.f;
#pragma unroll
    for (int dy = 0; dy < 3; ++dy)
#pragma unroll
      for (int dx = 0; dx < 3; ++dx)
        a = fmaf(r[dy][j + dx], wv[dy * 3 + dx], a);
    o_[j] = a;
  }
  int head = ch / 24, c = ch % 24;
  int h1 = y >> 6, hs = y & 63, w1 = x0 >> 6, ws0 = x0 & 63;
  int bh = (b << 3) + head;
  int rr = (c << 4) + (h1 << 2) + w1;
  *(ushort4*)&outb[((size_t)(bh * 384 + rr) << 12) + (hs << 6) + ws0] =
      make_ushort4(f2bf(o_[0]), f2bf(o_[1]), f2bf(o_[2]), f2bf(o_[3]));
}

// ---------------- fused mdc (v2): all 4 kernel sizes from one staged tile.
// tile 32x32, thread = 4-wide strip; b128 row loads, 24:1 FMA:LDS ratio.
// NOTE: the ~3.9e7 SQ_LDS_BANK_CONFLICT here are 2-way (free per m136);
// v3/v4/v5/v6 restructurings all regressed — do not re-litigate.
// Epilogue uses __expf + v_rcp (only delta vs the 636.8 µs round-10 state).
__global__ __launch_bounds__(256) void mdc_fused_kernel(
    const ushort* __restrict__ in, const float* __restrict__ w3,
    const float* __restrict__ w5, const float* __restrict__ w7,
    const float* __restrict__ w9, ushort* __restrict__ out) {
  __shared__ float s[4][40][40];
  const int bz = blockIdx.z;
  const int b = bz / 48, g = bz % 48;
  const int x0 = blockIdx.x << 5, y0 = blockIdx.y << 5;
  const ushort* inb = in + (((size_t)b * CDIM + 4 * g) << 16);
  // stage: 4ch x 40rows x 40cols, 4-elem chunks (never straddle 0/256)
  for (int idx = threadIdx.x; idx < 1600; idx += 256) {
    int rowid = idx / 10, c = idx % 10;
    int i = rowid / 40, yy = rowid % 40;
    int y = y0 + yy - 4;
    int xs = x0 + (c << 2) - 4;
    float4 v = make_float4(0.f, 0.f, 0.f, 0.f);
    if (y >= 0 && y < 256 && xs >= 0 && xs < 256) {
      ushort4 u = *(const ushort4*)&inb[((size_t)i << 16) + (size_t)y * 256 + xs];
      v = make_float4(bf2f(u.x), bf2f(u.y), bf2f(u.z), bf2f(u.w));
    }
    *(float4*)&s[i][yy][c << 2] = v;
  }
  __syncthreads();
  const int tx = threadIdx.x & 7;        // x-chunk (4 wide)
  const int ty = threadIdx.x >> 3;       // y 0..31
  float a3[4] = {}, a5[4] = {}, a7[4] = {}, a9[4] = {};
#pragma unroll 1
  for (int i = 0; i < 4; ++i) {
    const float* w9p = w9 + (g * 4 + i) * 81;
    const float* w7p = w7 + (g * 4 + i) * 49;
    const float* w5p = w5 + (g * 4 + i) * 25;
    const float* w3p = w3 + (g * 4 + i) * 9;
#pragma unroll
    for (int ky = 0; ky < 9; ++ky) {
      float row[12];
      *(float4*)&row[0] = *(const float4*)&s[i][ty + ky][(tx << 2)];
      *(float4*)&row[4] = *(const float4*)&s[i][ty + ky][(tx << 2) + 4];
      *(float4*)&row[8] = *(const float4*)&s[i][ty + ky][(tx << 2) + 8];
#pragma unroll
      for (int kx = 0; kx < 9; ++kx) {
        float w = w9p[ky * 9 + kx];
#pragma unroll
        for (int j = 0; j < 4; ++j) a9[j] = fmaf(row[j + kx], w, a9[j]);
      }
      if (ky >= 1 && ky <= 7) {
#pragma unroll
        for (int kx = 0; kx < 7; ++kx) {
          float w = w7p[(ky - 1) * 7 + kx];
#pragma unroll
          for (int j = 0; j < 4; ++j) a7[j] = fmaf(row[j + kx + 1], w, a7[j]);
        }
      }
      if (ky >= 2 && ky <= 6) {
#pragma unroll
        for (int kx = 0; kx < 5; ++kx) {
          float w = w5p[(ky - 2) * 5 + kx];
#pragma unroll
          for (int j = 0; j < 4; ++j) a5[j] = fmaf(row[j + kx + 2], w, a5[j]);
        }
      }
      if (ky >= 3 && ky <= 5) {
#pragma unroll
        for (int kx = 0; kx < 3; ++kx) {
          float w = w3p[(ky - 3) * 3 + kx];
#pragma unroll
          for (int j = 0; j < 4; ++j) a3[j] = fmaf(row[j + kx + 3], w, a3[j]);
        }
      }
    }
  }
  const int yo = y0 + ty, xo = x0 + (tx << 2);
#pragma unroll
  for (int sel = 0; sel < 4; ++sel) {
    const float* ap = (sel == 0) ? a3 : (sel == 1) ? a5 : (sel == 2) ? a7 : a9;
    int oc = sel * 48 + g;
    size_t off = (((size_t)b * CDIM + oc) << 16) + (size_t)yo * 256 + xo;
    ushort4 u = *(const ushort4*)&in[off];
    float s0 = __builtin_amdgcn_rcpf(1.f + __expf(-bf2f(u.x)));
    float s1 = __builtin_amdgcn_rcpf(1.f + __expf(-bf2f(u.y)));
    float s2 = __builtin_amdgcn_rcpf(1.f + __expf(-bf2f(u.z)));
    float s3 = __builtin_amdgcn_rcpf(1.f + __expf(-bf2f(u.w)));
    *(ushort4*)&out[off] = make_ushort4(f2bf(s0 * ap[0]), f2bf(s1 * ap[1]),
                                        f2bf(s2 * ap[2]), f2bf(s3 * ap[3]));
  }
}

// ---------------- inverse L2 norm per heads-row (bf16, 1 wave/row)
__global__ __launch_bounds__(256) void norm_bf16_kernel(
    const ushort* __restrict__ Qb, const ushort* __restrict__ Kb,
    float* __restrict__ nrm) {
  const int which = blockIdx.y;
  const int id = (blockIdx.x << 2) + (threadIdx.x >> 6);
  const int lane = threadIdx.x & 63;
  const ushort* row = (which ? Kb : Qb) + ((size_t)id << 12);
  float s = 0.f;
#pragma unroll
  for (int e = 0; e < 8; ++e) {
    uint4 u = *(const uint4*)&row[(e << 9) + (lane << 3)];
    uint us[4] = {u.x, u.y, u.z, u.w};
#pragma unroll
    for (int q = 0; q < 4; ++q) {
      float lo = __uint_as_float(us[q] << 16);
      float hi = __uint_as_float(us[q] & 0xffff0000u);
      s = fmaf(lo, lo, s);
      s = fmaf(hi, hi, s);
    }
  }
#pragma unroll
  for (int o = 32; o; o >>= 1) s += __shfl_down(s, o, 64);
  if (lane == 0) nrm[which * 6144 + id] = 1.f / fmaxf(sqrtf(s), 1e-12f);
}

// ---------------- QK^T partials: bf16 MFMA, 128x128 tile, split-K=4
__global__ __launch_bounds__(256) void qk_mfma_kernel(
    const ushort* __restrict__ Qb, const ushort* __restrict__ Kb,
    float* __restrict__ part) {
  __shared__ ushort as_[128][72];
  __shared__ ushort bs_[128][72];
  const int bz = blockIdx.z, bh = bz >> 2, ks = bz & 3;
  const int i0 = blockIdx.y << 7, j0 = blockIdx.x << 7;
  const int tid = threadIdx.x;
  const int wave = tid >> 6, lane = tid & 63;
  const int wr = wave >> 1, wc = wave & 1;
  const int lr = lane & 15, lk = lane >> 4;
  const size_t qbase = ((size_t)(bh * 384 + i0) << 12) + (ks << 10);
  const size_t kbase = ((size_t)(bh * 384 + j0) << 12) + (ks << 10);
  f32x4 acc[4][4] = {};
  for (int kt = 0; kt < 16; ++kt) {
#pragma unroll
    for (int e = 0; e < 4; ++e) {
      int chunk = (e << 8) + tid;
      int row = chunk >> 3, c8 = (chunk & 7) << 3;
      *(uint4*)&as_[row][c8] =
          *(const uint4*)&Qb[qbase + ((size_t)row << 12) + (kt << 6) + c8];
      *(uint4*)&bs_[row][c8] =
          *(const uint4*)&Kb[kbase + ((size_t)row << 12) + (kt << 6) + c8];
    }
    __syncthreads();
#pragma unroll
    for (int kk = 0; kk < 2; ++kk) {
      short8 aF[4], bF[4];
#pragma unroll
      for (int m = 0; m < 4; ++m)
        aF[m] = *(const short8*)&as_[(wr << 6) + (m << 4) + lr][(kk << 5) + (lk << 3)];
#pragma unroll
      for (int n = 0; n < 4; ++n)
        bF[n] = *(const short8*)&bs_[(wc << 6) + (n << 4) + lr][(kk << 5) + (lk << 3)];
#pragma unroll
      for (int m = 0; m < 4; ++m)
#pragma unroll
        for (int n = 0; n < 4; ++n)
          acc[m][n] =
              __builtin_amdgcn_mfma_f32_16x16x32_bf16(aF[m], bF[n], acc[m][n], 0, 0, 0);
    }
    __syncthreads();
  }
  float* pbase = part + (size_t)(ks * 16 + bh) * 384 * 384;
#pragma unroll
  for (int m = 0; m < 4; ++m)
#pragma unroll
    for (int reg = 0; reg < 4; ++reg) {
      int i = i0 + (wr << 6) + (m << 4) + (lk << 2) + reg;
#pragma unroll
      for (int n = 0; n < 4; ++n) {
        int j = j0 + (wc << 6) + (n << 4) + lr;
        pbase[(size_t)i * 384 + j] = acc[m][n][reg];
      }
    }
}

// ---------------- sum partials, scale, softmax, write bf16 P
__global__ __launch_bounds__(384) void softmax_kernel(
    const float* __restrict__ part, const float* __restrict__ nrm,
    const float* __restrict__ temp, ushort* __restrict__ Pb) {
  const int row = blockIdx.x;
  const int bh = row / 384;
  const int head = bh & 7;
  const int tid = threadIdx.x;
  const size_t off = (size_t)row * 384 + tid;
  float s = part[off] + part[off + 2359296] + part[off + 4718592] +
            part[off + 7077888];
  float v = s * temp[head] * nrm[row] * nrm[6144 + bh * 384 + tid];
  __shared__ float red[6];
  float m = v;
#pragma unroll
  for (int o = 32; o; o >>= 1) m = fmaxf(m, __shfl_down(m, o, 64));
  if ((tid & 63) == 0) red[tid >> 6] = m;
  __syncthreads();
  float bm = fmaxf(fmaxf(fmaxf(red[0], red[1]), fmaxf(red[2], red[3])),
                   fmaxf(red[4], red[5]));
  __syncthreads();
  float e = __expf(v - bm);
  float ss = e;
#pragma unroll
  for (int o = 32; o; o >>= 1) ss += __shfl_down(ss, o, 64);
  if ((tid & 63) == 0) red[tid >> 6] = ss;
  __syncthreads();
  float bs = red[0] + red[1] + red[2] + red[3] + red[4] + red[5];
  Pb[off] = f2bf(e * __builtin_amdgcn_rcpf(bs));
}

// ---------------- pack V: bf16 NCHW -> bf16 token-major [bh][t][384]
__global__ __launch_bounds__(256) void pack_v_kernel(
    const ushort* __restrict__ v1, ushort* __restrict__ Vb) {
  __shared__ ushort st[384][72];
  const int hs = blockIdx.x, bh = blockIdx.y;
  const int b = bh >> 3, head = bh & 7;
  const int tid = threadIdx.x;
#pragma unroll
  for (int e = 0; e < 12; ++e) {
    int idx = (e << 8) + tid;
    int r = idx >> 3, w8 = (idx & 7) << 3;
    *(uint4*)&st[r][w8] = *(const uint4*)&v1[rowbase(b, head, r, hs) + w8];
  }
  __syncthreads();
  const size_t vb0 = ((size_t)bh * 4096 + (hs << 6)) * 384;
#pragma unroll
  for (int e = 0; e < 12; ++e) {
    int chunk = (e << 8) + tid;
    int trow = chunk & 63, c8 = (chunk >> 6) << 3;
    ushort tmp[8];
#pragma unroll
    for (int q = 0; q < 8; ++q) tmp[q] = st[c8 + q][trow];
    *(uint4*)&Vb[vb0 + (size_t)trow * 384 + c8] = *(uint4*)tmp;
  }
}

// ---------------- O = P @ V : bf16 MFMA -> bf16 NCHW heads-merged
__global__ __launch_bounds__(256) void pv_mfma_kernel(
    const ushort* __restrict__ Pb, const ushort* __restrict__ Vb,
    ushort* __restrict__ outh) {
  __shared__ ushort as_[128][72];
  __shared__ ushort bs_[128][72];
  const int bh = blockIdx.z, b = bh >> 3, head = bh & 7;
  const int i0 = blockIdx.y << 7, t0 = blockIdx.x << 7;
  const int tid = threadIdx.x;
  const int wave = tid >> 6, lane = tid & 63;
  const int wr = wave >> 1, wc = wave & 1;
  const int lr = lane & 15, lk = lane >> 4;
  const size_t pbase = (size_t)(bh * 384 + i0) * 384;
  const size_t vbase = ((size_t)bh * 4096 + t0) * 384;
  f32x4 acc[4][4] = {};
  for (int kt = 0; kt < 6; ++kt) {
#pragma unroll
    for (int e = 0; e < 4; ++e) {
      int chunk = (e << 8) + tid;
      int row = chunk >> 3, c8 = (chunk & 7) << 3;
      *(uint4*)&as_[row][c8] =
          *(const uint4*)&Pb[pbase + (size_t)row * 384 + (kt << 6) + c8];
      *(uint4*)&bs_[row][c8] =
          *(const uint4*)&Vb[vbase + (size_t)row * 384 + (kt << 6) + c8];
    }
    __syncthreads();
#pragma unroll
    for (int kk = 0; kk < 2; ++kk) {
      short8 aF[4], bF[4];
#pragma unroll
      for (int m = 0; m < 4; ++m)
        aF[m] = *(const short8*)&as_[(wr << 6) + (m << 4) + lr][(kk << 5) + (lk << 3)];
#pragma unroll
      for (int n = 0; n < 4; ++n)
        bF[n] = *(const short8*)&bs_[(wc << 6) + (n << 4) + lr][(kk << 5) + (lk << 3)];
#pragma unroll
      for (int m = 0; m < 4; ++m)
#pragma unroll
        for (int n = 0; n < 4; ++n)
          acc[m][n] =
              __builtin_amdgcn_mfma_f32_16x16x32_bf16(aF[m], bF[n], acc[m][n], 0, 0, 0);
    }
    __syncthreads();
  }
#pragma unroll
  for (int m = 0; m < 4; ++m)
#pragma unroll
    for (int reg = 0; reg < 4; ++reg) {
      int i = i0 + (wr << 6) + (m << 4) + (lk << 2) + reg;
#pragma unroll
      for (int n = 0; n < 4; ++n) {
        int t = t0 + (wc << 6) + (n << 4) + lr;
        outh[rowbase(b, head, i, t >> 6) + (t & 63)] = f2bf(acc[m][n][reg]);
      }
    }
}

extern "C" void kernel_launch(void* const* d_in, const int* in_sizes, int n_in,
                              void* d_out, int out_size, void* d_ws,
                              size_t ws_size, hipStream_t stream) {
  const float* xu     = (const float*)d_in[0];
  const float* xd     = (const float*)d_in[1];
  const float* temp   = (const float*)d_in[2];
  const float* q1_w   = (const float*)d_in[3];
  const float* q1_b   = (const float*)d_in[4];
  const float* k1_w   = (const float*)d_in[5];
  const float* k1_b   = (const float*)d_in[6];
  const float* v1_w   = (const float*)d_in[7];
  const float* v1_b   = (const float*)d_in[8];
  const float* mdcq_w = (const float*)d_in[9];
  const float* mdck_w = (const float*)d_in[10];
  const float* mdc1_w = (const float*)d_in[11];
  const float* mdc2_w = (const float*)d_in[12];
  const float* mdc3_w = (const float*)d_in[13];
  const float* mdc4_w = (const float*)d_in[14];
  const float* proj_w = (const float*)d_in[15];
  const float* proj_b = (const float*)d_in[16];
  float* out = (float*)d_out;

  const size_t SZ = (size_t)2 * CDIM * HW * 2;   // bytes of one bf16 tensor
  char* W = (char*)d_ws;
  ushort* A0 = (ushort*)(W + 0 * SZ);    // Xut -> kpre
  ushort* A1 = (ushort*)(W + 1 * SZ);    // Xdt -> OH (heads-merged NCHW bf16)
  ushort* A2 = (ushort*)(W + 2 * SZ);    // qpre -> vpre -> OHt
  ushort* A3 = (ushort*)(W + 3 * SZ);    // Qb  -> v1 (mdc out)
  ushort* A4 = (ushort*)(W + 4 * SZ);    // Kb  -> Vb
  float*  PART = (float*)(W + 5 * SZ);                   // 4x16x384x384 fp32
  ushort* Pb   = (ushort*)(W + 5 * SZ + 37748736);       // bf16 P
  float*  NRM  = (float*)(W + 5 * SZ + 37748736 + 4718592);

  dim3 b256(256);
  dim3 gcast(1024, 2);
  dim3 gconv(256, 3, 2);

  // input casts to NHWC bf16
  cast_f32_nhwc_kernel<<<gcast, b256, 0, stream>>>(xu, A0);
  cast_f32_nhwc_kernel<<<gcast, b256, 0, stream>>>(xd, A1);
  // q branch
  conv_mfma_kernel<0><<<gconv, b256, 0, stream>>>(A0, q1_w, q1_b, A2);
  dw3x3_bf16_kernel<<<24576, b256, 0, stream>>>(A2, mdcq_w, A3);
  // k branch (A0 free after conv-q)
  conv_mfma_kernel<0><<<gconv, b256, 0, stream>>>(A1, k1_w, k1_b, A0);
  dw3x3_bf16_kernel<<<24576, b256, 0, stream>>>(A0, mdck_w, A4);
  // norms + attention + softmax
  norm_bf16_kernel<<<dim3(1536, 2), b256, 0, stream>>>(A3, A4, NRM);
  qk_mfma_kernel<<<dim3(3, 3, 64), b256, 0, stream>>>(A3, A4, PART);
  softmax_kernel<<<6144, dim3(384), 0, stream>>>(PART, NRM, temp, Pb);
  // v branch: conv (Xdt still in A1), fused mdc into A3 (Qb dead), pack to A4
  conv_mfma_kernel<0><<<gconv, b256, 0, stream>>>(A1, v1_w, v1_b, A2);
  mdc_fused_kernel<<<dim3(8, 8, 96), b256, 0, stream>>>(
      A2, mdc1_w, mdc2_w, mdc3_w, mdc4_w, A3);
  pack_v_kernel<<<dim3(64, 16), b256, 0, stream>>>(A3, A4);
  // O = P @ V -> heads-merged NCHW bf16 in A1 (Xdt dead)
  pv_mfma_kernel<<<dim3(32, 3, 16), b256, 0, stream>>>(Pb, A4, A1);
  // cast OH to NHWC, final projection -> fp32 d_out
  cast_bf16_nhwc_kernel<<<gcast, b256, 0, stream>>>(A1, A2);
  conv_mfma_kernel<1><<<gconv, b256, 0, stream>>>(A2, proj_w, proj_b, out);
}

// Round 13
// 634.765 us; speedup vs baseline: 1.0637x; 1.0158x over previous
//
#include <hip/hip_runtime.h>
#include <math.h>

#define CDIM 192
#define HW 65536

typedef __attribute__((ext_vector_type(8))) short short8;
typedef __attribute__((ext_vector_type(4))) float f32x4;

__device__ __forceinline__ ushort f2bf(float f) {
  uint u = __float_as_uint(f);
  uint r = (u + 0x7fffu + ((u >> 16) & 1u)) >> 16;
  return (ushort)r;
}
__device__ __forceinline__ float bf2f(ushort u) {
  return __uint_as_float(((uint)u) << 16);
}

// row r (0..383) of a head: c = r>>4, h1 = (r>>2)&3, w1 = r&3
// element offset of (b, head, r, hs, ws=0) in NCHW (2,192,256,256)
__device__ __forceinline__ size_t rowbase(int b, int head, int r, int hs) {
  int c = r >> 4, h1 = (r >> 2) & 3, w1 = r & 3;
  return ((size_t)(b * CDIM + head * 24 + c) << 16) +
         (size_t)((h1 << 6) + hs) * 256 + (w1 << 6);
}

// ---------------- cast+transpose: NCHW fp32 -> NHWC bf16  [b][p][192]
__global__ __launch_bounds__(256) void cast_f32_nhwc_kernel(
    const float* __restrict__ in, ushort* __restrict__ out) {
  __shared__ ushort T[64][200];          // stride 400B = 25*16 (b128-aligned)
  const int p0 = blockIdx.x << 6, b = blockIdx.y;
  const int tid = threadIdx.x;
#pragma unroll
  for (int it = 0; it < 12; ++it) {      // 192c x 64p fp32 = 3072 float4
    int idx = (it << 8) + tid;
    int c = idx >> 4, p4 = (idx & 15) << 2;
    float4 v = *(const float4*)&in[((size_t)(b * CDIM + c) << 16) + p0 + p4];
    T[p4 + 0][c] = f2bf(v.x);
    T[p4 + 1][c] = f2bf(v.y);
    T[p4 + 2][c] = f2bf(v.z);
    T[p4 + 3][c] = f2bf(v.w);
  }
  __syncthreads();
#pragma unroll
  for (int it = 0; it < 6; ++it) {       // 64p x 192c bf16 = 1536 uint4
    int idx = (it << 8) + tid;
    int p = idx / 24, c8 = (idx % 24) << 3;
    *(uint4*)&out[((size_t)(b * HW + p0 + p)) * CDIM + c8] =
        *(uint4*)&T[p][c8];
  }
}

// ---------------- cast+transpose: NCHW bf16 -> NHWC bf16
__global__ __launch_bounds__(256) void cast_bf16_nhwc_kernel(
    const ushort* __restrict__ in, ushort* __restrict__ out) {
  __shared__ ushort T[64][200];
  const int p0 = blockIdx.x << 6, b = blockIdx.y;
  const int tid = threadIdx.x;
#pragma unroll
  for (int it = 0; it < 6; ++it) {       // 192c x 64p bf16 = 1536 uint4
    int idx = (it << 8) + tid;
    int c = idx >> 3, p8 = (idx & 7) << 3;
    uint4 v = *(const uint4*)&in[((size_t)(b * CDIM + c) << 16) + p0 + p8];
    const ushort* pv = (const ushort*)&v;
#pragma unroll
    for (int q = 0; q < 8; ++q) T[p8 + q][c] = pv[q];
  }
  __syncthreads();
#pragma unroll
  for (int it = 0; it < 6; ++it) {
    int idx = (it << 8) + tid;
    int p = idx / 24, c8 = (idx % 24) << 3;
    *(uint4*)&out[((size_t)(b * HW + p0 + p)) * CDIM + c8] =
        *(uint4*)&T[p][c8];
  }
}

// ---------------- conv1x1 via bf16 MFMA: X NHWC bf16, W fp32 [o][c]
// tile 64o x 256p, K=192 in 3 chunks of 64. 4 waves, each 64o x 64p.
template <int OUTF32>
__global__ __launch_bounds__(256) void conv_mfma_kernel(
    const ushort* __restrict__ Xt, const float* __restrict__ w,
    const float* __restrict__ bias, void* __restrict__ outv) {
  __shared__ ushort WL[64][200];         // [o][c], stride 400B
  __shared__ ushort XL[256][72];         // [p][c-chunk 64], stride 144B
  const int p0 = blockIdx.x << 8;
  const int o0 = blockIdx.y << 6;
  const int b  = blockIdx.z;
  const int tid = threadIdx.x;
  const int wave = tid >> 6, lane = tid & 63;
  const int lr = lane & 15, lk = lane >> 4;
  // stage W (fp32 -> bf16), 64 x 192
#pragma unroll
  for (int it = 0; it < 12; ++it) {
    int idx = (it << 8) + tid;
    int o = idx / 48, c4 = (idx % 48) << 2;
    float4 v = *(const float4*)&w[(o0 + o) * CDIM + c4];
    ushort4 u = make_ushort4(f2bf(v.x), f2bf(v.y), f2bf(v.z), f2bf(v.w));
    *(ushort4*)&WL[o][c4] = u;
  }
  f32x4 acc[4][4] = {};
  const size_t xbase = ((size_t)(b * HW + p0)) * CDIM;
  for (int kt = 0; kt < 3; ++kt) {
    __syncthreads();
#pragma unroll
    for (int it = 0; it < 8; ++it) {     // 256p x 64c = 2048 uint4
      int idx = (it << 8) + tid;
      int p = idx >> 3, c8 = (idx & 7) << 3;
      *(uint4*)&XL[p][c8] =
          *(const uint4*)&Xt[xbase + (size_t)p * CDIM + kt * 64 + c8];
    }
    __syncthreads();
#pragma unroll
    for (int kk = 0; kk < 2; ++kk) {
      short8 aF[4], bF[4];
#pragma unroll
      for (int m = 0; m < 4; ++m)
        aF[m] = *(const short8*)&WL[(m << 4) + lr][kt * 64 + (kk << 5) + (lk << 3)];
#pragma unroll
      for (int n = 0; n < 4; ++n)
        bF[n] = *(const short8*)&XL[(wave << 6) + (n << 4) + lr][(kk << 5) + (lk << 3)];
#pragma unroll
      for (int m = 0; m < 4; ++m)
#pragma unroll
        for (int n = 0; n < 4; ++n)
          acc[m][n] =
              __builtin_amdgcn_mfma_f32_16x16x32_bf16(aF[m], bF[n], acc[m][n], 0, 0, 0);
    }
  }
#pragma unroll
  for (int m = 0; m < 4; ++m)
#pragma unroll
    for (int reg = 0; reg < 4; ++reg) {
      int i = o0 + (m << 4) + (lk << 2) + reg;
      float bo = bias[i];
      size_t ob = ((size_t)(b * CDIM + i) << 16) + p0 + (wave << 6) + lr;
#pragma unroll
      for (int n = 0; n < 4; ++n) {
        float v = acc[m][n][reg] + bo;
        if (OUTF32)
          ((float*)outv)[ob + (n << 4)] = v;
        else
          ((ushort*)outv)[ob + (n << 4)] = f2bf(v);
      }
    }
}

// ---------------- depthwise 3x3 on NCHW bf16 -> bf16 heads layout
__global__ __launch_bounds__(256) void dw3x3_bf16_kernel(
    const ushort* __restrict__ in, const float* __restrict__ wdw,
    ushort* __restrict__ outb) {
  size_t idx = ((size_t)blockIdx.x << 8) + threadIdx.x;
  int x0 = (int)(idx & 63) << 2;
  int y  = (int)((idx >> 6) & 255);
  int bc = (int)(idx >> 14);
  int ch = bc % CDIM, b = bc / CDIM;
  const ushort* ip = in + ((size_t)bc << 16);
  const float* wp = wdw + ch * 9;
  float wv[9];
#pragma unroll
  for (int k = 0; k < 9; ++k) wv[k] = wp[k];
  float r[3][6];
#pragma unroll
  for (int dy = 0; dy < 3; ++dy) {
    int yy = y + dy - 1;
    bool yok = (yy >= 0) && (yy < 256);
#pragma unroll
    for (int dx = 0; dx < 6; ++dx) {
      int xx = x0 + dx - 1;
      bool ok = yok && (xx >= 0) && (xx < 256);
      r[dy][dx] = ok ? bf2f(ip[(size_t)yy * 256 + xx]) : 0.f;
    }
  }
  float o_[4];
#pragma unroll
  for (int j = 0; j < 4; ++j) {
    float a = 0.f;
#pragma unroll
    for (int dy = 0; dy < 3; ++dy)
#pragma unroll
      for (int dx = 0; dx < 3; ++dx)
        a = fmaf(r[dy][j + dx], wv[dy * 3 + dx], a);
    o_[j] = a;
  }
  int head = ch / 24, c = ch % 24;
  int h1 = y >> 6, hs = y & 63, w1 = x0 >> 6, ws0 = x0 & 63;
  int bh = (b << 3) + head;
  int rr = (c << 4) + (h1 << 2) + w1;
  *(ushort4*)&outb[((size_t)(bh * 384 + rr) << 12) + (hs << 6) + ws0] =
      make_ushort4(f2bf(o_[0]), f2bf(o_[1]), f2bf(o_[2]), f2bf(o_[3]));
}

// ---------------- fused mdc (v2, round-10 exact): all 4 kernel sizes from
// one staged tile. tile 32x32, thread = 4-wide strip; b128 row loads,
// 24:1 FMA:LDS ratio. VGPR 44 is the occupancy sweet spot — epilogue must
// stay libm expf (r12: __expf here cost 12 VGPR -> occ 51->41%, net loss).
// The ~3.9e7 SQ_LDS_BANK_CONFLICT are 2-way (free per m136) — leave alone.
__global__ __launch_bounds__(256) void mdc_fused_kernel(
    const ushort* __restrict__ in, const float* __restrict__ w3,
    const float* __restrict__ w5, const float* __restrict__ w7,
    const float* __restrict__ w9, ushort* __restrict__ out) {
  __shared__ float s[4][40][40];
  const int bz = blockIdx.z;
  const int b = bz / 48, g = bz % 48;
  const int x0 = blockIdx.x << 5, y0 = blockIdx.y << 5;
  const ushort* inb = in + (((size_t)b * CDIM + 4 * g) << 16);
  // stage: 4ch x 40rows x 40cols, 4-elem chunks (never straddle 0/256)
  for (int idx = threadIdx.x; idx < 1600; idx += 256) {
    int rowid = idx / 10, c = idx % 10;
    int i = rowid / 40, yy = rowid % 40;
    int y = y0 + yy - 4;
    int xs = x0 + (c << 2) - 4;
    float4 v = make_float4(0.f, 0.f, 0.f, 0.f);
    if (y >= 0 && y < 256 && xs >= 0 && xs < 256) {
      ushort4 u = *(const ushort4*)&inb[((size_t)i << 16) + (size_t)y * 256 + xs];
      v = make_float4(bf2f(u.x), bf2f(u.y), bf2f(u.z), bf2f(u.w));
    }
    *(float4*)&s[i][yy][c << 2] = v;
  }
  __syncthreads();
  const int tx = threadIdx.x & 7;        // x-chunk (4 wide)
  const int ty = threadIdx.x >> 3;       // y 0..31
  float a3[4] = {}, a5[4] = {}, a7[4] = {}, a9[4] = {};
#pragma unroll 1
  for (int i = 0; i < 4; ++i) {
    const float* w9p = w9 + (g * 4 + i) * 81;
    const float* w7p = w7 + (g * 4 + i) * 49;
    const float* w5p = w5 + (g * 4 + i) * 25;
    const float* w3p = w3 + (g * 4 + i) * 9;
#pragma unroll
    for (int ky = 0; ky < 9; ++ky) {
      float row[12];
      *(float4*)&row[0] = *(const float4*)&s[i][ty + ky][(tx << 2)];
      *(float4*)&row[4] = *(const float4*)&s[i][ty + ky][(tx << 2) + 4];
      *(float4*)&row[8] = *(const float4*)&s[i][ty + ky][(tx << 2) + 8];
#pragma unroll
      for (int kx = 0; kx < 9; ++kx) {
        float w = w9p[ky * 9 + kx];
#pragma unroll
        for (int j = 0; j < 4; ++j) a9[j] = fmaf(row[j + kx], w, a9[j]);
      }
      if (ky >= 1 && ky <= 7) {
#pragma unroll
        for (int kx = 0; kx < 7; ++kx) {
          float w = w7p[(ky - 1) * 7 + kx];
#pragma unroll
          for (int j = 0; j < 4; ++j) a7[j] = fmaf(row[j + kx + 1], w, a7[j]);
        }
      }
      if (ky >= 2 && ky <= 6) {
#pragma unroll
        for (int kx = 0; kx < 5; ++kx) {
          float w = w5p[(ky - 2) * 5 + kx];
#pragma unroll
          for (int j = 0; j < 4; ++j) a5[j] = fmaf(row[j + kx + 2], w, a5[j]);
        }
      }
      if (ky >= 3 && ky <= 5) {
#pragma unroll
        for (int kx = 0; kx < 3; ++kx) {
          float w = w3p[(ky - 3) * 3 + kx];
#pragma unroll
          for (int j = 0; j < 4; ++j) a3[j] = fmaf(row[j + kx + 3], w, a3[j]);
        }
      }
    }
  }
  const int yo = y0 + ty, xo = x0 + (tx << 2);
#pragma unroll
  for (int sel = 0; sel < 4; ++sel) {
    const float* ap = (sel == 0) ? a3 : (sel == 1) ? a5 : (sel == 2) ? a7 : a9;
    int oc = sel * 48 + g;
    size_t off = (((size_t)b * CDIM + oc) << 16) + (size_t)yo * 256 + xo;
    ushort4 u = *(const ushort4*)&in[off];
    float s0 = 1.f / (1.f + expf(-bf2f(u.x)));
    float s1 = 1.f / (1.f + expf(-bf2f(u.y)));
    float s2 = 1.f / (1.f + expf(-bf2f(u.z)));
    float s3 = 1.f / (1.f + expf(-bf2f(u.w)));
    *(ushort4*)&out[off] = make_ushort4(f2bf(s0 * ap[0]), f2bf(s1 * ap[1]),
                                        f2bf(s2 * ap[2]), f2bf(s3 * ap[3]));
  }
}

// ---------------- inverse L2 norm per heads-row (bf16, 1 wave/row)
__global__ __launch_bounds__(256) void norm_bf16_kernel(
    const ushort* __restrict__ Qb, const ushort* __restrict__ Kb,
    float* __restrict__ nrm) {
  const int which = blockIdx.y;
  const int id = (blockIdx.x << 2) + (threadIdx.x >> 6);
  const int lane = threadIdx.x & 63;
  const ushort* row = (which ? Kb : Qb) + ((size_t)id << 12);
  float s = 0.f;
#pragma unroll
  for (int e = 0; e < 8; ++e) {
    uint4 u = *(const uint4*)&row[(e << 9) + (lane << 3)];
    uint us[4] = {u.x, u.y, u.z, u.w};
#pragma unroll
    for (int q = 0; q < 4; ++q) {
      float lo = __uint_as_float(us[q] << 16);
      float hi = __uint_as_float(us[q] & 0xffff0000u);
      s = fmaf(lo, lo, s);
      s = fmaf(hi, hi, s);
    }
  }
#pragma unroll
  for (int o = 32; o; o >>= 1) s += __shfl_down(s, o, 64);
  if (lane == 0) nrm[which * 6144 + id] = 1.f / fmaxf(sqrtf(s), 1e-12f);
}

// ---------------- QK^T partials: bf16 MFMA, 128x128 tile, split-K=4
__global__ __launch_bounds__(256) void qk_mfma_kernel(
    const ushort* __restrict__ Qb, const ushort* __restrict__ Kb,
    float* __restrict__ part) {
  __shared__ ushort as_[128][72];
  __shared__ ushort bs_[128][72];
  const int bz = blockIdx.z, bh = bz >> 2, ks = bz & 3;
  const int i0 = blockIdx.y << 7, j0 = blockIdx.x << 7;
  const int tid = threadIdx.x;
  const int wave = tid >> 6, lane = tid & 63;
  const int wr = wave >> 1, wc = wave & 1;
  const int lr = lane & 15, lk = lane >> 4;
  const size_t qbase = ((size_t)(bh * 384 + i0) << 12) + (ks << 10);
  const size_t kbase = ((size_t)(bh * 384 + j0) << 12) + (ks << 10);
  f32x4 acc[4][4] = {};
  for (int kt = 0; kt < 16; ++kt) {
#pragma unroll
    for (int e = 0; e < 4; ++e) {
      int chunk = (e << 8) + tid;
      int row = chunk >> 3, c8 = (chunk & 7) << 3;
      *(uint4*)&as_[row][c8] =
          *(const uint4*)&Qb[qbase + ((size_t)row << 12) + (kt << 6) + c8];
      *(uint4*)&bs_[row][c8] =
          *(const uint4*)&Kb[kbase + ((size_t)row << 12) + (kt << 6) + c8];
    }
    __syncthreads();
#pragma unroll
    for (int kk = 0; kk < 2; ++kk) {
      short8 aF[4], bF[4];
#pragma unroll
      for (int m = 0; m < 4; ++m)
        aF[m] = *(const short8*)&as_[(wr << 6) + (m << 4) + lr][(kk << 5) + (lk << 3)];
#pragma unroll
      for (int n = 0; n < 4; ++n)
        bF[n] = *(const short8*)&bs_[(wc << 6) + (n << 4) + lr][(kk << 5) + (lk << 3)];
#pragma unroll
      for (int m = 0; m < 4; ++m)
#pragma unroll
        for (int n = 0; n < 4; ++n)
          acc[m][n] =
              __builtin_amdgcn_mfma_f32_16x16x32_bf16(aF[m], bF[n], acc[m][n], 0, 0, 0);
    }
    __syncthreads();
  }
  float* pbase = part + (size_t)(ks * 16 + bh) * 384 * 384;
#pragma unroll
  for (int m = 0; m < 4; ++m)
#pragma unroll
    for (int reg = 0; reg < 4; ++reg) {
      int i = i0 + (wr << 6) + (m << 4) + (lk << 2) + reg;
#pragma unroll
      for (int n = 0; n < 4; ++n) {
        int j = j0 + (wc << 6) + (n << 4) + lr;
        pbase[(size_t)i * 384 + j] = acc[m][n][reg];
      }
    }
}

// ---------------- sum partials, scale, softmax, write bf16 P
__global__ __launch_bounds__(384) void softmax_kernel(
    const float* __restrict__ part, const float* __restrict__ nrm,
    const float* __restrict__ temp, ushort* __restrict__ Pb) {
  const int row = blockIdx.x;
  const int bh = row / 384;
  const int head = bh & 7;
  const int tid = threadIdx.x;
  const size_t off = (size_t)row * 384 + tid;
  float s = part[off] + part[off + 2359296] + part[off + 4718592] +
            part[off + 7077888];
  float v = s * temp[head] * nrm[row] * nrm[6144 + bh * 384 + tid];
  __shared__ float red[6];
  float m = v;
#pragma unroll
  for (int o = 32; o; o >>= 1) m = fmaxf(m, __shfl_down(m, o, 64));
  if ((tid & 63) == 0) red[tid >> 6] = m;
  __syncthreads();
  float bm = fmaxf(fmaxf(fmaxf(red[0], red[1]), fmaxf(red[2], red[3])),
                   fmaxf(red[4], red[5]));
  __syncthreads();
  float e = __expf(v - bm);
  float ss = e;
#pragma unroll
  for (int o = 32; o; o >>= 1) ss += __shfl_down(ss, o, 64);
  if ((tid & 63) == 0) red[tid >> 6] = ss;
  __syncthreads();
  float bs = red[0] + red[1] + red[2] + red[3] + red[4] + red[5];
  Pb[off] = f2bf(e * __builtin_amdgcn_rcpf(bs));
}

// ---------------- pack V: bf16 NCHW -> bf16 token-major [bh][t][384]
__global__ __launch_bounds__(256) void pack_v_kernel(
    const ushort* __restrict__ v1, ushort* __restrict__ Vb) {
  __shared__ ushort st[384][72];
  const int hs = blockIdx.x, bh = blockIdx.y;
  const int b = bh >> 3, head = bh & 7;
  const int tid = threadIdx.x;
#pragma unroll
  for (int e = 0; e < 12; ++e) {
    int idx = (e << 8) + tid;
    int r = idx >> 3, w8 = (idx & 7) << 3;
    *(uint4*)&st[r][w8] = *(const uint4*)&v1[rowbase(b, head, r, hs) + w8];
  }
  __syncthreads();
  const size_t vb0 = ((size_t)bh * 4096 + (hs << 6)) * 384;
#pragma unroll
  for (int e = 0; e < 12; ++e) {
    int chunk = (e << 8) + tid;
    int trow = chunk & 63, c8 = (chunk >> 6) << 3;
    ushort tmp[8];
#pragma unroll
    for (int q = 0; q < 8; ++q) tmp[q] = st[c8 + q][trow];
    *(uint4*)&Vb[vb0 + (size_t)trow * 384 + c8] = *(uint4*)tmp;
  }
}

// ---------------- O = P @ V : bf16 MFMA -> bf16 NCHW heads-merged
__global__ __launch_bounds__(256) void pv_mfma_kernel(
    const ushort* __restrict__ Pb, const ushort* __restrict__ Vb,
    ushort* __restrict__ outh) {
  __shared__ ushort as_[128][72];
  __shared__ ushort bs_[128][72];
  const int bh = blockIdx.z, b = bh >> 3, head = bh & 7;
  const int i0 = blockIdx.y << 7, t0 = blockIdx.x << 7;
  const int tid = threadIdx.x;
  const int wave = tid >> 6, lane = tid & 63;
  const int wr = wave >> 1, wc = wave & 1;
  const int lr = lane & 15, lk = lane >> 4;
  const size_t pbase = (size_t)(bh * 384 + i0) * 384;
  const size_t vbase = ((size_t)bh * 4096 + t0) * 384;
  f32x4 acc[4][4] = {};
  for (int kt = 0; kt < 6; ++kt) {
#pragma unroll
    for (int e = 0; e < 4; ++e) {
      int chunk = (e << 8) + tid;
      int row = chunk >> 3, c8 = (chunk & 7) << 3;
      *(uint4*)&as_[row][c8] =
          *(const uint4*)&Pb[pbase + (size_t)row * 384 + (kt << 6) + c8];
      *(uint4*)&bs_[row][c8] =
          *(const uint4*)&Vb[vbase + (size_t)row * 384 + (kt << 6) + c8];
    }
    __syncthreads();
#pragma unroll
    for (int kk = 0; kk < 2; ++kk) {
      short8 aF[4], bF[4];
#pragma unroll
      for (int m = 0; m < 4; ++m)
        aF[m] = *(const short8*)&as_[(wr << 6) + (m << 4) + lr][(kk << 5) + (lk << 3)];
#pragma unroll
      for (int n = 0; n < 4; ++n)
        bF[n] = *(const short8*)&bs_[(wc << 6) + (n << 4) + lr][(kk << 5) + (lk << 3)];
#pragma unroll
      for (int m = 0; m < 4; ++m)
#pragma unroll
        for (int n = 0; n < 4; ++n)
          acc[m][n] =
              __builtin_amdgcn_mfma_f32_16x16x32_bf16(aF[m], bF[n], acc[m][n], 0, 0, 0);
    }
    __syncthreads();
  }
#pragma unroll
  for (int m = 0; m < 4; ++m)
#pragma unroll
    for (int reg = 0; reg < 4; ++reg) {
      int i = i0 + (wr << 6) + (m << 4) + (lk << 2) + reg;
#pragma unroll
      for (int n = 0; n < 4; ++n) {
        int t = t0 + (wc << 6) + (n << 4) + lr;
        outh[rowbase(b, head, i, t >> 6) + (t & 63)] = f2bf(acc[m][n][reg]);
      }
    }
}

extern "C" void kernel_launch(void* const* d_in, const int* in_sizes, int n_in,
                              void* d_out, int out_size, void* d_ws,
                              size_t ws_size, hipStream_t stream) {
  const float* xu     = (const float*)d_in[0];
  const float* xd     = (const float*)d_in[1];
  const float* temp   = (const float*)d_in[2];
  const float* q1_w   = (const float*)d_in[3];
  const float* q1_b   = (const float*)d_in[4];
  const float* k1_w   = (const float*)d_in[5];
  const float* k1_b   = (const float*)d_in[6];
  const float* v1_w   = (const float*)d_in[7];
  const float* v1_b   = (const float*)d_in[8];
  const float* mdcq_w = (const float*)d_in[9];
  const float* mdck_w = (const float*)d_in[10];
  const float* mdc1_w = (const float*)d_in[11];
  const float* mdc2_w = (const float*)d_in[12];
  const float* mdc3_w = (const float*)d_in[13];
  const float* mdc4_w = (const float*)d_in[14];
  const float* proj_w = (const float*)d_in[15];
  const float* proj_b = (const float*)d_in[16];
  float* out = (float*)d_out;

  const size_t SZ = (size_t)2 * CDIM * HW * 2;   // bytes of one bf16 tensor
  char* W = (char*)d_ws;
  ushort* A0 = (ushort*)(W + 0 * SZ);    // Xut -> kpre
  ushort* A1 = (ushort*)(W + 1 * SZ);    // Xdt -> OH (heads-merged NCHW bf16)
  ushort* A2 = (ushort*)(W + 2 * SZ);    // qpre -> vpre -> OHt
  ushort* A3 = (ushort*)(W + 3 * SZ);    // Qb  -> v1 (mdc out)
  ushort* A4 = (ushort*)(W + 4 * SZ);    // Kb  -> Vb
  float*  PART = (float*)(W + 5 * SZ);                   // 4x16x384x384 fp32
  ushort* Pb   = (ushort*)(W + 5 * SZ + 37748736);       // bf16 P
  float*  NRM  = (float*)(W + 5 * SZ + 37748736 + 4718592);

  dim3 b256(256);
  dim3 gcast(1024, 2);
  dim3 gconv(256, 3, 2);

  // input casts to NHWC bf16
  cast_f32_nhwc_kernel<<<gcast, b256, 0, stream>>>(xu, A0);
  cast_f32_nhwc_kernel<<<gcast, b256, 0, stream>>>(xd, A1);
  // q branch
  conv_mfma_kernel<0><<<gconv, b256, 0, stream>>>(A0, q1_w, q1_b, A2);
  dw3x3_bf16_kernel<<<24576, b256, 0, stream>>>(A2, mdcq_w, A3);
  // k branch (A0 free after conv-q)
  conv_mfma_kernel<0><<<gconv, b256, 0, stream>>>(A1, k1_w, k1_b, A0);
  dw3x3_bf16_kernel<<<24576, b256, 0, stream>>>(A0, mdck_w, A4);
  // norms + attention + softmax
  norm_bf16_kernel<<<dim3(1536, 2), b256, 0, stream>>>(A3, A4, NRM);
  qk_mfma_kernel<<<dim3(3, 3, 64), b256, 0, stream>>>(A3, A4, PART);
  softmax_kernel<<<6144, dim3(384), 0, stream>>>(PART, NRM, temp, Pb);
  // v branch: conv (Xdt still in A1), fused mdc into A3 (Qb dead), pack to A4
  conv_mfma_kernel<0><<<gconv, b256, 0, stream>>>(A1, v1_w, v1_b, A2);
  mdc_fused_kernel<<<dim3(8, 8, 96), b256, 0, stream>>>(
      A2, mdc1_w, mdc2_w, mdc3_w, mdc4_w, A3);
  pack_v_kernel<<<dim3(64, 16), b256, 0, stream>>>(A3, A4);
  // O = P @ V -> heads-merged NCHW bf16 in A1 (Xdt dead)
  pv_mfma_kernel<<<dim3(32, 3, 16), b256, 0, stream>>>(Pb, A4, A1);
  // cast OH to NHWC, final projection -> fp32 d_out
  cast_bf16_nhwc_kernel<<<gcast, b256, 0, stream>>>(A1, A2);
  conv_mfma_kernel<1><<<gconv, b256, 0, stream>>>(A2, proj_w, proj_b, out);
}

// Round 14
// 620.209 us; speedup vs baseline: 1.0887x; 1.0235x over previous
//
#include <hip/hip_runtime.h>
#include <math.h>

#define CDIM 192
#define HW 65536

typedef __attribute__((ext_vector_type(8))) short short8;
typedef __attribute__((ext_vector_type(4))) float f32x4;

__device__ __forceinline__ ushort f2bf(float f) {
  uint u = __float_as_uint(f);
  uint r = (u + 0x7fffu + ((u >> 16) & 1u)) >> 16;
  return (ushort)r;
}
__device__ __forceinline__ float bf2f(ushort u) {
  return __uint_as_float(((uint)u) << 16);
}

// row r (0..383) of a head: c = r>>4, h1 = (r>>2)&3, w1 = r&3
// element offset of (b, head, r, hs, ws=0) in NCHW (2,192,256,256)
__device__ __forceinline__ size_t rowbase(int b, int head, int r, int hs) {
  int c = r >> 4, h1 = (r >> 2) & 3, w1 = r & 3;
  return ((size_t)(b * CDIM + head * 24 + c) << 16) +
         (size_t)((h1 << 6) + hs) * 256 + (w1 << 6);
}

// ---------------- cast+transpose: NCHW fp32 -> NHWC bf16  [b][p][192]
__global__ __launch_bounds__(256) void cast_f32_nhwc_kernel(
    const float* __restrict__ in, ushort* __restrict__ out) {
  __shared__ ushort T[64][200];          // stride 400B = 25*16 (b128-aligned)
  const int p0 = blockIdx.x << 6, b = blockIdx.y;
  const int tid = threadIdx.x;
#pragma unroll
  for (int it = 0; it < 12; ++it) {      // 192c x 64p fp32 = 3072 float4
    int idx = (it << 8) + tid;
    int c = idx >> 4, p4 = (idx & 15) << 2;
    float4 v = *(const float4*)&in[((size_t)(b * CDIM + c) << 16) + p0 + p4];
    T[p4 + 0][c] = f2bf(v.x);
    T[p4 + 1][c] = f2bf(v.y);
    T[p4 + 2][c] = f2bf(v.z);
    T[p4 + 3][c] = f2bf(v.w);
  }
  __syncthreads();
#pragma unroll
  for (int it = 0; it < 6; ++it) {       // 64p x 192c bf16 = 1536 uint4
    int idx = (it << 8) + tid;
    int p = idx / 24, c8 = (idx % 24) << 3;
    *(uint4*)&out[((size_t)(b * HW + p0 + p)) * CDIM + c8] =
        *(uint4*)&T[p][c8];
  }
}

// ---------------- cast+transpose: NCHW bf16 -> NHWC bf16
__global__ __launch_bounds__(256) void cast_bf16_nhwc_kernel(
    const ushort* __restrict__ in, ushort* __restrict__ out) {
  __shared__ ushort T[64][200];
  const int p0 = blockIdx.x << 6, b = blockIdx.y;
  const int tid = threadIdx.x;
#pragma unroll
  for (int it = 0; it < 6; ++it) {       // 192c x 64p bf16 = 1536 uint4
    int idx = (it << 8) + tid;
    int c = idx >> 3, p8 = (idx & 7) << 3;
    uint4 v = *(const uint4*)&in[((size_t)(b * CDIM + c) << 16) + p0 + p8];
    const ushort* pv = (const ushort*)&v;
#pragma unroll
    for (int q = 0; q < 8; ++q) T[p8 + q][c] = pv[q];
  }
  __syncthreads();
#pragma unroll
  for (int it = 0; it < 6; ++it) {
    int idx = (it << 8) + tid;
    int p = idx / 24, c8 = (idx % 24) << 3;
    *(uint4*)&out[((size_t)(b * HW + p0 + p)) * CDIM + c8] =
        *(uint4*)&T[p][c8];
  }
}

// ---------------- conv1x1 via bf16 MFMA: X NHWC bf16, W fp32 [o][c]
// tile 64o x 256p, K=192 in 3 chunks of 64. 4 waves, each 64o x 64p.
template <int OUTF32>
__global__ __launch_bounds__(256) void conv_mfma_kernel(
    const ushort* __restrict__ Xt, const float* __restrict__ w,
    const float* __restrict__ bias, void* __restrict__ outv) {
  __shared__ ushort WL[64][200];         // [o][c], stride 400B
  __shared__ ushort XL[256][72];         // [p][c-chunk 64], stride 144B
  const int p0 = blockIdx.x << 8;
  const int o0 = blockIdx.y << 6;
  const int b  = blockIdx.z;
  const int tid = threadIdx.x;
  const int wave = tid >> 6, lane = tid & 63;
  const int lr = lane & 15, lk = lane >> 4;
  // stage W (fp32 -> bf16), 64 x 192
#pragma unroll
  for (int it = 0; it < 12; ++it) {
    int idx = (it << 8) + tid;
    int o = idx / 48, c4 = (idx % 48) << 2;
    float4 v = *(const float4*)&w[(o0 + o) * CDIM + c4];
    ushort4 u = make_ushort4(f2bf(v.x), f2bf(v.y), f2bf(v.z), f2bf(v.w));
    *(ushort4*)&WL[o][c4] = u;
  }
  f32x4 acc[4][4] = {};
  const size_t xbase = ((size_t)(b * HW + p0)) * CDIM;
  for (int kt = 0; kt < 3; ++kt) {
    __syncthreads();
#pragma unroll
    for (int it = 0; it < 8; ++it) {     // 256p x 64c = 2048 uint4
      int idx = (it << 8) + tid;
      int p = idx >> 3, c8 = (idx & 7) << 3;
      *(uint4*)&XL[p][c8] =
          *(const uint4*)&Xt[xbase + (size_t)p * CDIM + kt * 64 + c8];
    }
    __syncthreads();
#pragma unroll
    for (int kk = 0; kk < 2; ++kk) {
      short8 aF[4], bF[4];
#pragma unroll
      for (int m = 0; m < 4; ++m)
        aF[m] = *(const short8*)&WL[(m << 4) + lr][kt * 64 + (kk << 5) + (lk << 3)];
#pragma unroll
      for (int n = 0; n < 4; ++n)
        bF[n] = *(const short8*)&XL[(wave << 6) + (n << 4) + lr][(kk << 5) + (lk << 3)];
#pragma unroll
      for (int m = 0; m < 4; ++m)
#pragma unroll
        for (int n = 0; n < 4; ++n)
          acc[m][n] =
              __builtin_amdgcn_mfma_f32_16x16x32_bf16(aF[m], bF[n], acc[m][n], 0, 0, 0);
    }
  }
#pragma unroll
  for (int m = 0; m < 4; ++m)
#pragma unroll
    for (int reg = 0; reg < 4; ++reg) {
      int i = o0 + (m << 4) + (lk << 2) + reg;
      float bo = bias[i];
      size_t ob = ((size_t)(b * CDIM + i) << 16) + p0 + (wave << 6) + lr;
#pragma unroll
      for (int n = 0; n < 4; ++n) {
        float v = acc[m][n][reg] + bo;
        if (OUTF32)
          ((float*)outv)[ob + (n << 4)] = v;
        else
          ((ushort*)outv)[ob + (n << 4)] = f2bf(v);
      }
    }
}

// ---------------- depthwise 3x3 on NCHW bf16 -> bf16 heads layout
__global__ __launch_bounds__(256) void dw3x3_bf16_kernel(
    const ushort* __restrict__ in, const float* __restrict__ wdw,
    ushort* __restrict__ outb) {
  size_t idx = ((size_t)blockIdx.x << 8) + threadIdx.x;
  int x0 = (int)(idx & 63) << 2;
  int y  = (int)((idx >> 6) & 255);
  int bc = (int)(idx >> 14);
  int ch = bc % CDIM, b = bc / CDIM;
  const ushort* ip = in + ((size_t)bc << 16);
  const float* wp = wdw + ch * 9;
  float wv[9];
#pragma unroll
  for (int k = 0; k < 9; ++k) wv[k] = wp[k];
  float r[3][6];
#pragma unroll
  for (int dy = 0; dy < 3; ++dy) {
    int yy = y + dy - 1;
    bool yok = (yy >= 0) && (yy < 256);
#pragma unroll
    for (int dx = 0; dx < 6; ++dx) {
      int xx = x0 + dx - 1;
      bool ok = yok && (xx >= 0) && (xx < 256);
      r[dy][dx] = ok ? bf2f(ip[(size_t)yy * 256 + xx]) : 0.f;
    }
  }
  float o_[4];
#pragma unroll
  for (int j = 0; j < 4; ++j) {
    float a = 0.f;
#pragma unroll
    for (int dy = 0; dy < 3; ++dy)
#pragma unroll
      for (int dx = 0; dx < 3; ++dx)
        a = fmaf(r[dy][j + dx], wv[dy * 3 + dx], a);
    o_[j] = a;
  }
  int head = ch / 24, c = ch % 24;
  int h1 = y >> 6, hs = y & 63, w1 = x0 >> 6, ws0 = x0 & 63;
  int bh = (b << 3) + head;
  int rr = (c << 4) + (h1 << 2) + w1;
  *(ushort4*)&outb[((size_t)(bh * 384 + rr) << 12) + (hs << 6) + ws0] =
      make_ushort4(f2bf(o_[0]), f2bf(o_[1]), f2bf(o_[2]), f2bf(o_[3]));
}

// ---------------- fused mdc (v2, round-10 exact): all 4 kernel sizes from
// one staged tile. tile 32x32, thread = 4-wide strip; b128 row loads,
// 24:1 FMA:LDS ratio. VGPR 44 is the occupancy sweet spot — epilogue must
// stay libm expf (r12: __expf here cost 12 VGPR -> occ 51->41%, net loss).
// The ~3.9e7 SQ_LDS_BANK_CONFLICT are 2-way (free per m136) — leave alone.
__global__ __launch_bounds__(256) void mdc_fused_kernel(
    const ushort* __restrict__ in, const float* __restrict__ w3,
    const float* __restrict__ w5, const float* __restrict__ w7,
    const float* __restrict__ w9, ushort* __restrict__ out) {
  __shared__ float s[4][40][40];
  const int bz = blockIdx.z;
  const int b = bz / 48, g = bz % 48;
  const int x0 = blockIdx.x << 5, y0 = blockIdx.y << 5;
  const ushort* inb = in + (((size_t)b * CDIM + 4 * g) << 16);
  // stage: 4ch x 40rows x 40cols, 4-elem chunks (never straddle 0/256)
  for (int idx = threadIdx.x; idx < 1600; idx += 256) {
    int rowid = idx / 10, c = idx % 10;
    int i = rowid / 40, yy = rowid % 40;
    int y = y0 + yy - 4;
    int xs = x0 + (c << 2) - 4;
    float4 v = make_float4(0.f, 0.f, 0.f, 0.f);
    if (y >= 0 && y < 256 && xs >= 0 && xs < 256) {
      ushort4 u = *(const ushort4*)&inb[((size_t)i << 16) + (size_t)y * 256 + xs];
      v = make_float4(bf2f(u.x), bf2f(u.y), bf2f(u.z), bf2f(u.w));
    }
    *(float4*)&s[i][yy][c << 2] = v;
  }
  __syncthreads();
  const int tx = threadIdx.x & 7;        // x-chunk (4 wide)
  const int ty = threadIdx.x >> 3;       // y 0..31
  float a3[4] = {}, a5[4] = {}, a7[4] = {}, a9[4] = {};
#pragma unroll 1
  for (int i = 0; i < 4; ++i) {
    const float* w9p = w9 + (g * 4 + i) * 81;
    const float* w7p = w7 + (g * 4 + i) * 49;
    const float* w5p = w5 + (g * 4 + i) * 25;
    const float* w3p = w3 + (g * 4 + i) * 9;
#pragma unroll
    for (int ky = 0; ky < 9; ++ky) {
      float row[12];
      *(float4*)&row[0] = *(const float4*)&s[i][ty + ky][(tx << 2)];
      *(float4*)&row[4] = *(const float4*)&s[i][ty + ky][(tx << 2) + 4];
      *(float4*)&row[8] = *(const float4*)&s[i][ty + ky][(tx << 2) + 8];
#pragma unroll
      for (int kx = 0; kx < 9; ++kx) {
        float w = w9p[ky * 9 + kx];
#pragma unroll
        for (int j = 0; j < 4; ++j) a9[j] = fmaf(row[j + kx], w, a9[j]);
      }
      if (ky >= 1 && ky <= 7) {
#pragma unroll
        for (int kx = 0; kx < 7; ++kx) {
          float w = w7p[(ky - 1) * 7 + kx];
#pragma unroll
          for (int j = 0; j < 4; ++j) a7[j] = fmaf(row[j + kx + 1], w, a7[j]);
        }
      }
      if (ky >= 2 && ky <= 6) {
#pragma unroll
        for (int kx = 0; kx < 5; ++kx) {
          float w = w5p[(ky - 2) * 5 + kx];
#pragma unroll
          for (int j = 0; j < 4; ++j) a5[j] = fmaf(row[j + kx + 2], w, a5[j]);
        }
      }
      if (ky >= 3 && ky <= 5) {
#pragma unroll
        for (int kx = 0; kx < 3; ++kx) {
          float w = w3p[(ky - 3) * 3 + kx];
#pragma unroll
          for (int j = 0; j < 4; ++j) a3[j] = fmaf(row[j + kx + 3], w, a3[j]);
        }
      }
    }
  }
  const int yo = y0 + ty, xo = x0 + (tx << 2);
#pragma unroll
  for (int sel = 0; sel < 4; ++sel) {
    const float* ap = (sel == 0) ? a3 : (sel == 1) ? a5 : (sel == 2) ? a7 : a9;
    int oc = sel * 48 + g;
    size_t off = (((size_t)b * CDIM + oc) << 16) + (size_t)yo * 256 + xo;
    ushort4 u = *(const ushort4*)&in[off];
    float s0 = 1.f / (1.f + expf(-bf2f(u.x)));
    float s1 = 1.f / (1.f + expf(-bf2f(u.y)));
    float s2 = 1.f / (1.f + expf(-bf2f(u.z)));
    float s3 = 1.f / (1.f + expf(-bf2f(u.w)));
    *(ushort4*)&out[off] = make_ushort4(f2bf(s0 * ap[0]), f2bf(s1 * ap[1]),
                                        f2bf(s2 * ap[2]), f2bf(s3 * ap[3]));
  }
}

// ---------------- inverse L2 norm per heads-row (bf16, 1 wave/row)
__global__ __launch_bounds__(256) void norm_bf16_kernel(
    const ushort* __restrict__ Qb, const ushort* __restrict__ Kb,
    float* __restrict__ nrm) {
  const int which = blockIdx.y;
  const int id = (blockIdx.x << 2) + (threadIdx.x >> 6);
  const int lane = threadIdx.x & 63;
  const ushort* row = (which ? Kb : Qb) + ((size_t)id << 12);
  float s = 0.f;
#pragma unroll
  for (int e = 0; e < 8; ++e) {
    uint4 u = *(const uint4*)&row[(e << 9) + (lane << 3)];
    uint us[4] = {u.x, u.y, u.z, u.w};
#pragma unroll
    for (int q = 0; q < 4; ++q) {
      float lo = __uint_as_float(us[q] << 16);
      float hi = __uint_as_float(us[q] & 0xffff0000u);
      s = fmaf(lo, lo, s);
      s = fmaf(hi, hi, s);
    }
  }
#pragma unroll
  for (int o = 32; o; o >>= 1) s += __shfl_down(s, o, 64);
  if (lane == 0) nrm[which * 6144 + id] = 1.f / fmaxf(sqrtf(s), 1e-12f);
}

// ---------------- QK^T partials: bf16 MFMA, 128x128 tile, split-K=2
// (r14: split-K 4->2 — halves PART traffic; 288 blocks still > 256 CUs)
__global__ __launch_bounds__(256) void qk_mfma_kernel(
    const ushort* __restrict__ Qb, const ushort* __restrict__ Kb,
    float* __restrict__ part) {
  __shared__ ushort as_[128][72];
  __shared__ ushort bs_[128][72];
  const int bz = blockIdx.z, bh = bz >> 1, ks = bz & 1;
  const int i0 = blockIdx.y << 7, j0 = blockIdx.x << 7;
  const int tid = threadIdx.x;
  const int wave = tid >> 6, lane = tid & 63;
  const int wr = wave >> 1, wc = wave & 1;
  const int lr = lane & 15, lk = lane >> 4;
  const size_t qbase = ((size_t)(bh * 384 + i0) << 12) + (ks << 11);
  const size_t kbase = ((size_t)(bh * 384 + j0) << 12) + (ks << 11);
  f32x4 acc[4][4] = {};
  for (int kt = 0; kt < 32; ++kt) {
#pragma unroll
    for (int e = 0; e < 4; ++e) {
      int chunk = (e << 8) + tid;
      int row = chunk >> 3, c8 = (chunk & 7) << 3;
      *(uint4*)&as_[row][c8] =
          *(const uint4*)&Qb[qbase + ((size_t)row << 12) + (kt << 6) + c8];
      *(uint4*)&bs_[row][c8] =
          *(const uint4*)&Kb[kbase + ((size_t)row << 12) + (kt << 6) + c8];
    }
    __syncthreads();
#pragma unroll
    for (int kk = 0; kk < 2; ++kk) {
      short8 aF[4], bF[4];
#pragma unroll
      for (int m = 0; m < 4; ++m)
        aF[m] = *(const short8*)&as_[(wr << 6) + (m << 4) + lr][(kk << 5) + (lk << 3)];
#pragma unroll
      for (int n = 0; n < 4; ++n)
        bF[n] = *(const short8*)&bs_[(wc << 6) + (n << 4) + lr][(kk << 5) + (lk << 3)];
#pragma unroll
      for (int m = 0; m < 4; ++m)
#pragma unroll
        for (int n = 0; n < 4; ++n)
          acc[m][n] =
              __builtin_amdgcn_mfma_f32_16x16x32_bf16(aF[m], bF[n], acc[m][n], 0, 0, 0);
    }
    __syncthreads();
  }
  float* pbase = part + (size_t)(ks * 16 + bh) * 384 * 384;
#pragma unroll
  for (int m = 0; m < 4; ++m)
#pragma unroll
    for (int reg = 0; reg < 4; ++reg) {
      int i = i0 + (wr << 6) + (m << 4) + (lk << 2) + reg;
#pragma unroll
      for (int n = 0; n < 4; ++n) {
        int j = j0 + (wc << 6) + (n << 4) + lr;
        pbase[(size_t)i * 384 + j] = acc[m][n][reg];
      }
    }
}

// ---------------- sum 2 partials, scale, softmax, write bf16 P
__global__ __launch_bounds__(384) void softmax_kernel(
    const float* __restrict__ part, const float* __restrict__ nrm,
    const float* __restrict__ temp, ushort* __restrict__ Pb) {
  const int row = blockIdx.x;
  const int bh = row / 384;
  const int head = bh & 7;
  const int tid = threadIdx.x;
  const size_t off = (size_t)row * 384 + tid;
  float s = part[off] + part[off + 2359296];
  float v = s * temp[head] * nrm[row] * nrm[6144 + bh * 384 + tid];
  __shared__ float red[6];
  float m = v;
#pragma unroll
  for (int o = 32; o; o >>= 1) m = fmaxf(m, __shfl_down(m, o, 64));
  if ((tid & 63) == 0) red[tid >> 6] = m;
  __syncthreads();
  float bm = fmaxf(fmaxf(fmaxf(red[0], red[1]), fmaxf(red[2], red[3])),
                   fmaxf(red[4], red[5]));
  __syncthreads();
  float e = __expf(v - bm);
  float ss = e;
#pragma unroll
  for (int o = 32; o; o >>= 1) ss += __shfl_down(ss, o, 64);
  if ((tid & 63) == 0) red[tid >> 6] = ss;
  __syncthreads();
  float bs = red[0] + red[1] + red[2] + red[3] + red[4] + red[5];
  Pb[off] = f2bf(e * __builtin_amdgcn_rcpf(bs));
}

// ---------------- pack V: bf16 NCHW -> bf16 token-major [bh][t][384]
__global__ __launch_bounds__(256) void pack_v_kernel(
    const ushort* __restrict__ v1, ushort* __restrict__ Vb) {
  __shared__ ushort st[384][72];
  const int hs = blockIdx.x, bh = blockIdx.y;
  const int b = bh >> 3, head = bh & 7;
  const int tid = threadIdx.x;
#pragma unroll
  for (int e = 0; e < 12; ++e) {
    int idx = (e << 8) + tid;
    int r = idx >> 3, w8 = (idx & 7) << 3;
    *(uint4*)&st[r][w8] = *(const uint4*)&v1[rowbase(b, head, r, hs) + w8];
  }
  __syncthreads();
  const size_t vb0 = ((size_t)bh * 4096 + (hs << 6)) * 384;
#pragma unroll
  for (int e = 0; e < 12; ++e) {
    int chunk = (e << 8) + tid;
    int trow = chunk & 63, c8 = (chunk >> 6) << 3;
    ushort tmp[8];
#pragma unroll
    for (int q = 0; q < 8; ++q) tmp[q] = st[c8 + q][trow];
    *(uint4*)&Vb[vb0 + (size_t)trow * 384 + c8] = *(uint4*)tmp;
  }
}

// ---------------- O = P @ V : bf16 MFMA -> bf16 NCHW heads-merged
__global__ __launch_bounds__(256) void pv_mfma_kernel(
    const ushort* __restrict__ Pb, const ushort* __restrict__ Vb,
    ushort* __restrict__ outh) {
  __shared__ ushort as_[128][72];
  __shared__ ushort bs_[128][72];
  const int bh = blockIdx.z, b = bh >> 3, head = bh & 7;
  const int i0 = blockIdx.y << 7, t0 = blockIdx.x << 7;
  const int tid = threadIdx.x;
  const int wave = tid >> 6, lane = tid & 63;
  const int wr = wave >> 1, wc = wave & 1;
  const int lr = lane & 15, lk = lane >> 4;
  const size_t pbase = (size_t)(bh * 384 + i0) * 384;
  const size_t vbase = ((size_t)bh * 4096 + t0) * 384;
  f32x4 acc[4][4] = {};
  for (int kt = 0; kt < 6; ++kt) {
#pragma unroll
    for (int e = 0; e < 4; ++e) {
      int chunk = (e << 8) + tid;
      int row = chunk >> 3, c8 = (chunk & 7) << 3;
      *(uint4*)&as_[row][c8] =
          *(const uint4*)&Pb[pbase + (size_t)row * 384 + (kt << 6) + c8];
      *(uint4*)&bs_[row][c8] =
          *(const uint4*)&Vb[vbase + (size_t)row * 384 + (kt << 6) + c8];
    }
    __syncthreads();
#pragma unroll
    for (int kk = 0; kk < 2; ++kk) {
      short8 aF[4], bF[4];
#pragma unroll
      for (int m = 0; m < 4; ++m)
        aF[m] = *(const short8*)&as_[(wr << 6) + (m << 4) + lr][(kk << 5) + (lk << 3)];
#pragma unroll
      for (int n = 0; n < 4; ++n)
        bF[n] = *(const short8*)&bs_[(wc << 6) + (n << 4) + lr][(kk << 5) + (lk << 3)];
#pragma unroll
      for (int m = 0; m < 4; ++m)
#pragma unroll
        for (int n = 0; n < 4; ++n)
          acc[m][n] =
              __builtin_amdgcn_mfma_f32_16x16x32_bf16(aF[m], bF[n], acc[m][n], 0, 0, 0);
    }
    __syncthreads();
  }
#pragma unroll
  for (int m = 0; m < 4; ++m)
#pragma unroll
    for (int reg = 0; reg < 4; ++reg) {
      int i = i0 + (wr << 6) + (m << 4) + (lk << 2) + reg;
#pragma unroll
      for (int n = 0; n < 4; ++n) {
        int t = t0 + (wc << 6) + (n << 4) + lr;
        outh[rowbase(b, head, i, t >> 6) + (t & 63)] = f2bf(acc[m][n][reg]);
      }
    }
}

extern "C" void kernel_launch(void* const* d_in, const int* in_sizes, int n_in,
                              void* d_out, int out_size, void* d_ws,
                              size_t ws_size, hipStream_t stream) {
  const float* xu     = (const float*)d_in[0];
  const float* xd     = (const float*)d_in[1];
  const float* temp   = (const float*)d_in[2];
  const float* q1_w   = (const float*)d_in[3];
  const float* q1_b   = (const float*)d_in[4];
  const float* k1_w   = (const float*)d_in[5];
  const float* k1_b   = (const float*)d_in[6];
  const float* v1_w   = (const float*)d_in[7];
  const float* v1_b   = (const float*)d_in[8];
  const float* mdcq_w = (const float*)d_in[9];
  const float* mdck_w = (const float*)d_in[10];
  const float* mdc1_w = (const float*)d_in[11];
  const float* mdc2_w = (const float*)d_in[12];
  const float* mdc3_w = (const float*)d_in[13];
  const float* mdc4_w = (const float*)d_in[14];
  const float* proj_w = (const float*)d_in[15];
  const float* proj_b = (const float*)d_in[16];
  float* out = (float*)d_out;

  const size_t SZ = (size_t)2 * CDIM * HW * 2;   // bytes of one bf16 tensor
  char* W = (char*)d_ws;
  ushort* A0 = (ushort*)(W + 0 * SZ);    // Xut -> kpre
  ushort* A1 = (ushort*)(W + 1 * SZ);    // Xdt -> OH (heads-merged NCHW bf16)
  ushort* A2 = (ushort*)(W + 2 * SZ);    // qpre -> vpre -> OHt
  ushort* A3 = (ushort*)(W + 3 * SZ);    // Qb  -> v1 (mdc out)
  ushort* A4 = (ushort*)(W + 4 * SZ);    // Kb  -> Vb
  float*  PART = (float*)(W + 5 * SZ);                   // 2x16x384x384 fp32
  ushort* Pb   = (ushort*)(W + 5 * SZ + 18874368);       // bf16 P
  float*  NRM  = (float*)(W + 5 * SZ + 18874368 + 4718592);

  dim3 b256(256);
  dim3 gcast(1024, 2);
  dim3 gconv(256, 3, 2);

  // input casts to NHWC bf16
  cast_f32_nhwc_kernel<<<gcast, b256, 0, stream>>>(xu, A0);
  cast_f32_nhwc_kernel<<<gcast, b256, 0, stream>>>(xd, A1);
  // q branch
  conv_mfma_kernel<0><<<gconv, b256, 0, stream>>>(A0, q1_w, q1_b, A2);
  dw3x3_bf16_kernel<<<24576, b256, 0, stream>>>(A2, mdcq_w, A3);
  // k branch (A0 free after conv-q)
  conv_mfma_kernel<0><<<gconv, b256, 0, stream>>>(A1, k1_w, k1_b, A0);
  dw3x3_bf16_kernel<<<24576, b256, 0, stream>>>(A0, mdck_w, A4);
  // norms + attention + softmax
  norm_bf16_kernel<<<dim3(1536, 2), b256, 0, stream>>>(A3, A4, NRM);
  qk_mfma_kernel<<<dim3(3, 3, 32), b256, 0, stream>>>(A3, A4, PART);
  softmax_kernel<<<6144, dim3(384), 0, stream>>>(PART, NRM, temp, Pb);
  // v branch: conv (Xdt still in A1), fused mdc into A3 (Qb dead), pack to A4
  conv_mfma_kernel<0><<<gconv, b256, 0, stream>>>(A1, v1_w, v1_b, A2);
  mdc_fused_kernel<<<dim3(8, 8, 96), b256, 0, stream>>>(
      A2, mdc1_w, mdc2_w, mdc3_w, mdc4_w, A3);
  pack_v_kernel<<<dim3(64, 16), b256, 0, stream>>>(A3, A4);
  // O = P @ V -> heads-merged NCHW bf16 in A1 (Xdt dead)
  pv_mfma_kernel<<<dim3(32, 3, 16), b256, 0, stream>>>(Pb, A4, A1);
  // cast OH to NHWC, final projection -> fp32 d_out
  cast_bf16_nhwc_kernel<<<gcast, b256, 0, stream>>>(A1, A2);
  conv_mfma_kernel<1><<<gconv, b256, 0, stream>>>(A2, proj_w, proj_b, out);
}